// Round 1
// baseline (760.994 us; speedup 1.0000x reference)
//
#include <hip/hip_runtime.h>
#include <cstdint>
#include <cstddef>

typedef __bf16 bf16;
typedef __bf16 bf16x4 __attribute__((ext_vector_type(4)));
typedef __bf16 bf16x8 __attribute__((ext_vector_type(8)));
typedef float  f32x4  __attribute__((ext_vector_type(4)));

#define EPS 1e-5f

// ---------------------------------------------------------------------------
// async global->LDS, 16B per lane. LDS dest is wave-uniform base + lane*16.
// ---------------------------------------------------------------------------
__device__ __forceinline__ void load_lds16(const void* g, void* l) {
    typedef __attribute__((address_space(1))) void gvoid;
    typedef __attribute__((address_space(3))) void lvoid;
    gvoid* gp = (gvoid*)(unsigned long long)(uintptr_t)g;
    // generic LDS pointer = aperture_hi | offset_lo32 -> truncation yields LDS offset
    lvoid* lp = (lvoid*)(unsigned int)(uintptr_t)l;
    __builtin_amdgcn_global_load_lds(gp, lp, 16, 0, 0);
}

// ---------------------------------------------------------------------------
// small prep kernels
// ---------------------------------------------------------------------------
__global__ void convert_x(const float* __restrict__ x, bf16* __restrict__ xb) {
    size_t i = ((size_t)blockIdx.x * 256 + threadIdx.x) * 4;
    float4 v = *(const float4*)&x[i];
    bf16x4 o;
    o[0] = (bf16)v.x; o[1] = (bf16)v.y; o[2] = (bf16)v.z; o[3] = (bf16)v.w;
    *(bf16x4*)&xb[i] = o;
}

template<int K>
__global__ void transpose_w(const float* __restrict__ W, bf16* __restrict__ Wt) {
    int idx = blockIdx.x * 256 + threadIdx.x;   // over 512*K outputs, Wt[n][k]
    int n = idx / K, k = idx % K;
    Wt[idx] = (bf16)W[k * 512 + n];
}

__global__ void scalebias(const float* __restrict__ b, const float* __restrict__ g,
                          const float* __restrict__ be, const float* __restrict__ m,
                          const float* __restrict__ v, float* __restrict__ s,
                          float* __restrict__ t) {
    int j = blockIdx.x * 256 + threadIdx.x;   // 512
    float sj = g[j] * rsqrtf(v[j] + EPS);
    s[j] = sj;
    t[j] = (b[j] - m[j]) * sj + be[j];
}

// ---------------------------------------------------------------------------
// m97-structure GEMM: C[M,512] = relu( (A[M,K] @ Wt[512,K]^T) * s + t ), bf16 out
// 128x128 tile, BK=32, 4 waves (2x2), 16x16x32 bf16 MFMA, global_load_lds w=16
// ---------------------------------------------------------------------------
template<int K>
__global__ __launch_bounds__(256, 2)
void gemm_bt(const bf16* __restrict__ A, const bf16* __restrict__ Bt,
             const float* __restrict__ sc, const float* __restrict__ bi,
             bf16* __restrict__ C)
{
    __shared__ bf16 As[128 * 32];
    __shared__ bf16 Bs[128 * 32];
    const int tid  = threadIdx.x;
    const int lane = tid & 63;
    const int wid  = tid >> 6;
    const int wm   = wid >> 1;           // 0..1
    const int wn   = wid & 1;            // 0..1
    const size_t m0 = (size_t)blockIdx.x * 128;
    const int    n0 = blockIdx.y * 128;

    const int r0 = tid >> 2;             // staging row (round 0)
    const int cc = tid & 3;              // 8-elem chunk within 32-col row

    // wave-uniform LDS bases: chunk idx = round*256 + w*64 + lane, byte = idx*16
    bf16* AsW0 = &As[((tid & 192)      ) * 8];
    bf16* AsW1 = &As[((tid & 192) + 256) * 8];
    bf16* BsW0 = &Bs[((tid & 192)      ) * 8];
    bf16* BsW1 = &Bs[((tid & 192) + 256) * 8];

    f32x4 acc[4][4] = {};
    const int quad = lane >> 4;
    const int l16  = lane & 15;

    for (int k0 = 0; k0 < K; k0 += 32) {
        load_lds16(&A [(m0 +       r0) * K + k0 + cc * 8], AsW0);
        load_lds16(&A [(m0 + 64 +  r0) * K + k0 + cc * 8], AsW1);
        load_lds16(&Bt[(size_t)(n0 +      r0) * K + k0 + cc * 8], BsW0);
        load_lds16(&Bt[(size_t)(n0 + 64 + r0) * K + k0 + cc * 8], BsW1);
        __syncthreads();   // drains vmcnt -> LDS visible

        bf16x8 af[4], bfr[4];
        #pragma unroll
        for (int i = 0; i < 4; i++)
            af[i] = *(const bf16x8*)&As[(wm * 64 + i * 16 + l16) * 32 + quad * 8];
        #pragma unroll
        for (int j = 0; j < 4; j++)
            bfr[j] = *(const bf16x8*)&Bs[(wn * 64 + j * 16 + l16) * 32 + quad * 8];
        #pragma unroll
        for (int i = 0; i < 4; i++)
            #pragma unroll
            for (int j = 0; j < 4; j++)
                acc[i][j] = __builtin_amdgcn_mfma_f32_16x16x32_bf16(af[i], bfr[j], acc[i][j], 0, 0, 0);
        __syncthreads();   // before next staging overwrites LDS
    }

    // epilogue: C/D layout col = lane&15, row = quad*4 + r  [m89/m91 verified]
    #pragma unroll
    for (int j = 0; j < 4; j++) {
        const int col = n0 + wn * 64 + j * 16 + l16;
        const float s = sc[col], t = bi[col];
        #pragma unroll
        for (int i = 0; i < 4; i++) {
            const size_t rowb = m0 + wm * 64 + i * 16 + quad * 4;
            #pragma unroll
            for (int r = 0; r < 4; r++) {
                float v = acc[i][j][r] * s + t;
                v = v > 0.f ? v : 0.f;
                C[(rowb + r) * 512 + col] = (bf16)v;
            }
        }
    }
}

// ---------------------------------------------------------------------------
// A[N,8] = h4[N,512](bf16) @ Wa[512,8](f32)
// ---------------------------------------------------------------------------
__global__ __launch_bounds__(256)
void compute_A(const bf16* __restrict__ h, const float* __restrict__ Wa,
               float* __restrict__ A)
{
    __shared__ float WaL[512 * 8];
    const int tid = threadIdx.x;
    for (int i = tid; i < 4096; i += 256) WaL[i] = Wa[i];
    __syncthreads();
    const size_t row = (size_t)blockIdx.x * 32 + (tid >> 3);
    const int r = tid & 7;
    const bf16* hp = h + row * 512;
    float acc = 0.f;
    #pragma unroll 4
    for (int k8 = 0; k8 < 64; k8++) {
        bf16x8 hv = *(const bf16x8*)&hp[k8 * 8];
        #pragma unroll
        for (int j = 0; j < 8; j++)
            acc += (float)hv[j] * WaL[(k8 * 8 + j) * 8 + r];
    }
    A[row * 8 + r] = acc;
}

// ---------------------------------------------------------------------------
// per-segment: softmax over L for 8 cols + penalty contribution
// ---------------------------------------------------------------------------
__global__ __launch_bounds__(256)
void seg_softmax(const float* __restrict__ A, float* __restrict__ Asg,
                 float* __restrict__ pen)
{
    __shared__ float AsL[1024 * 8];
    __shared__ float red[256];
    __shared__ float amax[8], asum[8];
    const int b = blockIdx.x, tid = threadIdx.x;
    const float* Ab = A + (size_t)b * 8192;
    for (int i = tid * 4; i < 8192; i += 1024)
        *(float4*)&AsL[i] = *(const float4*)&Ab[i];
    __syncthreads();
    const int r = tid & 7, chunk = tid >> 3;     // 32 chunks x 32 rows
    float pm = -1e30f;
    for (int l = chunk * 32; l < chunk * 32 + 32; l++) pm = fmaxf(pm, AsL[l * 8 + r]);
    red[tid] = pm;
    __syncthreads();
    if (tid < 8) {
        float m = -1e30f;
        for (int c = 0; c < 32; c++) m = fmaxf(m, red[c * 8 + tid]);
        amax[tid] = m;
    }
    __syncthreads();
    const float mr = amax[r];
    float ps = 0.f;
    for (int l = chunk * 32; l < chunk * 32 + 32; l++) {
        float e = expf(AsL[l * 8 + r] - mr);
        AsL[l * 8 + r] = e;
        ps += e;
    }
    red[tid] = ps;
    __syncthreads();
    if (tid < 8) {
        float s = 0.f;
        for (int c = 0; c < 32; c++) s += red[c * 8 + tid];
        asum[tid] = s;
    }
    __syncthreads();
    const float inv = 1.f / asum[r];
    for (int l = chunk * 32; l < chunk * 32 + 32; l++) AsL[l * 8 + r] *= inv;
    __syncthreads();
    for (int i = tid * 4; i < 8192; i += 1024)
        *(float4*)&Asg[(size_t)b * 8192 + i] = *(const float4*)&AsL[i];
    // penalty: sum_{r,s} ((As^T As)[r,s] - 1)^2
    float pp = 0.f;
    if (tid < 64) {
        const int rr = tid >> 3, ss = tid & 7;
        float dot = 0.f;
        for (int l = 0; l < 1024; l++) dot += AsL[l * 8 + rr] * AsL[l * 8 + ss];
        float d = dot - 1.f;
        pp = d * d;
    }
    red[tid] = pp;
    __syncthreads();
    if (tid == 0) {
        float s = 0.f;
        for (int i = 0; i < 64; i++) s += red[i];
        atomicAdd(pen, s);
    }
}

// ---------------------------------------------------------------------------
// pooled[b, r, :] = sum_l As[b,l,r] * h[b,l,:]   (grid: 64 x 4 col-chunks)
// ---------------------------------------------------------------------------
__global__ __launch_bounds__(256)
void pooled_k(const float* __restrict__ Asg, const bf16* __restrict__ h,
              float* __restrict__ pooled)
{
    const int b = blockIdx.x;
    const int cc0 = blockIdx.y * 128;
    const int tid = threadIdx.x;
    const int c = tid & 127, rg = tid >> 7;      // rg: r-group 0/1 (4 r each)
    float a0 = 0, a1 = 0, a2 = 0, a3 = 0;
    const float* Asb = Asg + (size_t)b * 8192 + rg * 4;
    const bf16* hb = h + (size_t)b * 1024 * 512 + cc0 + c;
    for (int l = 0; l < 1024; l++) {
        float4 a = *(const float4*)&Asb[(size_t)l * 8];
        float hv = (float)hb[(size_t)l * 512];
        a0 += a.x * hv; a1 += a.y * hv; a2 += a.z * hv; a3 += a.w * hv;
    }
    float* pb = pooled + (size_t)b * 4096 + (rg * 4) * 512 + cc0 + c;
    pb[0] = a0; pb[512] = a1; pb[1024] = a2; pb[1536] = a3;
}

// ---------------------------------------------------------------------------
// per-segment mean / unbiased std of x
// ---------------------------------------------------------------------------
__global__ __launch_bounds__(256)
void seg_stats(const float* __restrict__ x, float* __restrict__ mean,
               float* __restrict__ stdv)
{
    const int b = blockIdx.x, d = threadIdx.x;   // 256 dims
    const float* xb = x + (size_t)b * 1024 * 256 + d;
    float s = 0.f, s2 = 0.f;
    for (int l = 0; l < 1024; l++) {
        float v = xb[(size_t)l * 256];
        s += v; s2 += v * v;
    }
    float m = s * (1.f / 1024.f);
    float var = (s2 - s * m) * (1.f / 1023.f);
    mean[b * 256 + d] = m;
    stdv[b * 256 + d] = sqrtf(fmaxf(var, 0.f));
}

// ---------------------------------------------------------------------------
// head: feat[4608] @ Wo1 -> BN+relu -> @ Wo2 -> log_softmax; also emit penalty
// ---------------------------------------------------------------------------
__global__ __launch_bounds__(128)
void final_k(const float* __restrict__ pooled, const float* __restrict__ mean,
             const float* __restrict__ stdv, const float* __restrict__ Wo1,
             const float* __restrict__ bo1, const float* __restrict__ go,
             const float* __restrict__ beo, const float* __restrict__ mo,
             const float* __restrict__ vo, const float* __restrict__ Wo2,
             const float* __restrict__ bo2, const float* __restrict__ pen,
             float* __restrict__ out)
{
    __shared__ float feat[4608];
    __shared__ float o[128];
    __shared__ float lg[4];
    const int b = blockIdx.x, tid = threadIdx.x;
    for (int i = tid; i < 4096; i += 128) feat[i] = pooled[(size_t)b * 4096 + i];
    for (int i = tid; i < 256; i += 128) {
        feat[4096 + i] = mean[b * 256 + i];
        feat[4352 + i] = stdv[b * 256 + i];
    }
    __syncthreads();
    float z = 0.f;
    #pragma unroll 8
    for (int i = 0; i < 4608; i++) z += feat[i] * Wo1[(size_t)i * 128 + tid];
    float s = go[tid] * rsqrtf(vo[tid] + EPS);
    float t = (bo1[tid] - mo[tid]) * s + beo[tid];
    float ov = z * s + t;
    o[tid] = ov > 0.f ? ov : 0.f;
    __syncthreads();
    if (tid < 4) {
        float acc = bo2[tid];
        for (int j = 0; j < 128; j++) acc += o[j] * Wo2[j * 4 + tid];
        lg[tid] = acc;
    }
    __syncthreads();
    if (tid == 0) {
        float m = fmaxf(fmaxf(lg[0], lg[1]), fmaxf(lg[2], lg[3]));
        float sum = 0.f;
        for (int k = 0; k < 4; k++) sum += expf(lg[k] - m);
        float lse = m + logf(sum);
        for (int k = 0; k < 4; k++) out[b * 4 + k] = lg[k] - lse;
        if (b == 0) out[256] = pen[0];
    }
}

// ---------------------------------------------------------------------------
extern "C" void kernel_launch(void* const* d_in, const int* in_sizes, int n_in,
                              void* d_out, int out_size, void* d_ws, size_t ws_size,
                              hipStream_t stream)
{
    const float* x   = (const float*)d_in[0];
    // d_in[1] = length (all == L, unused)
    const float* Wa  = (const float*)d_in[2];
    const float* Wo1 = (const float*)d_in[3];
    const float* bo1 = (const float*)d_in[4];
    const float* go  = (const float*)d_in[5];
    const float* beo = (const float*)d_in[6];
    const float* mo  = (const float*)d_in[7];
    const float* vo  = (const float*)d_in[8];
    const float* Wo2 = (const float*)d_in[9];
    const float* bo2 = (const float*)d_in[10];
    const float *W[4], *bb[4], *gg[4], *be[4], *mm[4], *vv[4];
    for (int l = 0; l < 4; l++) {
        W[l]  = (const float*)d_in[11 + 6 * l + 0];
        bb[l] = (const float*)d_in[11 + 6 * l + 1];
        gg[l] = (const float*)d_in[11 + 6 * l + 2];
        be[l] = (const float*)d_in[11 + 6 * l + 3];
        mm[l] = (const float*)d_in[11 + 6 * l + 4];
        vv[l] = (const float*)d_in[11 + 6 * l + 5];
    }

    char* w = (char*)d_ws;
    bf16* xb  = (bf16*)w;  w += (size_t)65536 * 256 * 2;   // 32 MB
    bf16* hA  = (bf16*)w;  w += (size_t)65536 * 512 * 2;   // 64 MB
    bf16* hB  = (bf16*)w;  w += (size_t)65536 * 512 * 2;   // 64 MB
    bf16* w1t = (bf16*)w;  w += (size_t)512 * 256 * 2;
    bf16* w2t = (bf16*)w;  w += (size_t)512 * 512 * 2;
    bf16* w3t = (bf16*)w;  w += (size_t)512 * 512 * 2;
    bf16* w4t = (bf16*)w;  w += (size_t)512 * 512 * 2;
    float* sb = (float*)w; w += (size_t)4 * 1024 * 4;      // [layer][s|t][512]
    float* Ab = (float*)w; w += (size_t)65536 * 8 * 4;
    float* As = (float*)w; w += (size_t)65536 * 8 * 4;
    float* pl = (float*)w; w += (size_t)64 * 4096 * 4;
    float* mn = (float*)w; w += (size_t)64 * 256 * 4;
    float* sd = (float*)w; w += (size_t)64 * 256 * 4;
    float* pen = (float*)w;

    hipMemsetAsync(pen, 0, sizeof(float), stream);
    convert_x<<<16384, 256, 0, stream>>>(x, xb);
    transpose_w<256><<<512, 256, 0, stream>>>(W[0], w1t);
    transpose_w<512><<<1024, 256, 0, stream>>>(W[1], w2t);
    transpose_w<512><<<1024, 256, 0, stream>>>(W[2], w3t);
    transpose_w<512><<<1024, 256, 0, stream>>>(W[3], w4t);
    for (int l = 0; l < 4; l++)
        scalebias<<<2, 256, 0, stream>>>(bb[l], gg[l], be[l], mm[l], vv[l],
                                         sb + l * 1024, sb + l * 1024 + 512);

    gemm_bt<256><<<dim3(512, 4), 256, 0, stream>>>(xb, w1t, sb + 0,    sb + 512,  hA);
    gemm_bt<512><<<dim3(512, 4), 256, 0, stream>>>(hA, w2t, sb + 1024, sb + 1536, hB);
    gemm_bt<512><<<dim3(512, 4), 256, 0, stream>>>(hB, w3t, sb + 2048, sb + 2560, hA);
    gemm_bt<512><<<dim3(512, 4), 256, 0, stream>>>(hA, w4t, sb + 3072, sb + 3584, hB);

    compute_A<<<2048, 256, 0, stream>>>(hB, Wa, Ab);
    seg_softmax<<<64, 256, 0, stream>>>(Ab, As, pen);
    pooled_k<<<dim3(64, 4), 256, 0, stream>>>(As, hB, pl);
    seg_stats<<<64, 256, 0, stream>>>(x, mn, sd);
    final_k<<<64, 128, 0, stream>>>(pl, mn, sd, Wo1, bo1, go, beo, mo, vo,
                                    Wo2, bo2, pen, (float*)d_out);
}

// Round 2
// 527.321 us; speedup vs baseline: 1.4431x; 1.4431x over previous
//
#include <hip/hip_runtime.h>
#include <cstdint>
#include <cstddef>

typedef __bf16 bf16;
typedef __bf16 bf16x4 __attribute__((ext_vector_type(4)));
typedef __bf16 bf16x8 __attribute__((ext_vector_type(8)));
typedef float  f32x4  __attribute__((ext_vector_type(4)));

#define EPS 1e-5f

// ---------------------------------------------------------------------------
// async global->LDS, 16B per lane. LDS dest is wave-uniform base + lane*16.
// ---------------------------------------------------------------------------
__device__ __forceinline__ void load_lds16(const void* g, void* l) {
    typedef __attribute__((address_space(1))) void gvoid;
    typedef __attribute__((address_space(3))) void lvoid;
    gvoid* gp = (gvoid*)(unsigned long long)(uintptr_t)g;
    lvoid* lp = (lvoid*)(unsigned int)(uintptr_t)l;
    __builtin_amdgcn_global_load_lds(gp, lp, 16, 0, 0);
}

// ---------------------------------------------------------------------------
// small prep kernels
// ---------------------------------------------------------------------------
__global__ void convert_x(const float* __restrict__ x, bf16* __restrict__ xb) {
    size_t i = ((size_t)blockIdx.x * 256 + threadIdx.x) * 4;
    float4 v = *(const float4*)&x[i];
    bf16x4 o;
    o[0] = (bf16)v.x; o[1] = (bf16)v.y; o[2] = (bf16)v.z; o[3] = (bf16)v.w;
    *(bf16x4*)&xb[i] = o;
}

template<int K>
__global__ void transpose_w(const float* __restrict__ W, bf16* __restrict__ Wt) {
    int idx = blockIdx.x * 256 + threadIdx.x;   // over 512*K outputs, Wt[n][k]
    int n = idx / K, k = idx % K;
    Wt[idx] = (bf16)W[k * 512 + n];
}

__global__ void scalebias(const float* __restrict__ b, const float* __restrict__ g,
                          const float* __restrict__ be, const float* __restrict__ m,
                          const float* __restrict__ v, float* __restrict__ s,
                          float* __restrict__ t) {
    int j = blockIdx.x * 256 + threadIdx.x;   // 512
    float sj = g[j] * rsqrtf(v[j] + EPS);
    s[j] = sj;
    t[j] = (b[j] - m[j]) * sj + be[j];
}

// ---------------------------------------------------------------------------
// m97-structure GEMM: C[M,512] = relu( (A[M,K] @ Wt[512,K]^T) * s + t ), bf16 out
// ---------------------------------------------------------------------------
template<int K>
__global__ __launch_bounds__(256, 2)
void gemm_bt(const bf16* __restrict__ A, const bf16* __restrict__ Bt,
             const float* __restrict__ sc, const float* __restrict__ bi,
             bf16* __restrict__ C)
{
    __shared__ bf16 As[128 * 32];
    __shared__ bf16 Bs[128 * 32];
    const int tid  = threadIdx.x;
    const int lane = tid & 63;
    const int wid  = tid >> 6;
    const int wm   = wid >> 1;
    const int wn   = wid & 1;
    const size_t m0 = (size_t)blockIdx.x * 128;
    const int    n0 = blockIdx.y * 128;

    const int r0 = tid >> 2;
    const int cc = tid & 3;

    bf16* AsW0 = &As[((tid & 192)      ) * 8];
    bf16* AsW1 = &As[((tid & 192) + 256) * 8];
    bf16* BsW0 = &Bs[((tid & 192)      ) * 8];
    bf16* BsW1 = &Bs[((tid & 192) + 256) * 8];

    f32x4 acc[4][4] = {};
    const int quad = lane >> 4;
    const int l16  = lane & 15;

    for (int k0 = 0; k0 < K; k0 += 32) {
        load_lds16(&A [(m0 +       r0) * K + k0 + cc * 8], AsW0);
        load_lds16(&A [(m0 + 64 +  r0) * K + k0 + cc * 8], AsW1);
        load_lds16(&Bt[(size_t)(n0 +      r0) * K + k0 + cc * 8], BsW0);
        load_lds16(&Bt[(size_t)(n0 + 64 + r0) * K + k0 + cc * 8], BsW1);
        __syncthreads();

        bf16x8 af[4], bfr[4];
        #pragma unroll
        for (int i = 0; i < 4; i++)
            af[i] = *(const bf16x8*)&As[(wm * 64 + i * 16 + l16) * 32 + quad * 8];
        #pragma unroll
        for (int j = 0; j < 4; j++)
            bfr[j] = *(const bf16x8*)&Bs[(wn * 64 + j * 16 + l16) * 32 + quad * 8];
        #pragma unroll
        for (int i = 0; i < 4; i++)
            #pragma unroll
            for (int j = 0; j < 4; j++)
                acc[i][j] = __builtin_amdgcn_mfma_f32_16x16x32_bf16(af[i], bfr[j], acc[i][j], 0, 0, 0);
        __syncthreads();
    }

    #pragma unroll
    for (int j = 0; j < 4; j++) {
        const int col = n0 + wn * 64 + j * 16 + l16;
        const float s = sc[col], t = bi[col];
        #pragma unroll
        for (int i = 0; i < 4; i++) {
            const size_t rowb = m0 + wm * 64 + i * 16 + quad * 4;
            #pragma unroll
            for (int r = 0; r < 4; r++) {
                float v = acc[i][j][r] * s + t;
                v = v > 0.f ? v : 0.f;
                C[(rowb + r) * 512 + col] = (bf16)v;
            }
        }
    }
}

// ---------------------------------------------------------------------------
// A[N,8] = h4[N,512](bf16) @ Wa[512,8](f32)
// ---------------------------------------------------------------------------
__global__ __launch_bounds__(256)
void compute_A(const bf16* __restrict__ h, const float* __restrict__ Wa,
               float* __restrict__ A)
{
    __shared__ float WaL[512 * 8];
    const int tid = threadIdx.x;
    for (int i = tid; i < 4096; i += 256) WaL[i] = Wa[i];
    __syncthreads();
    const size_t row = (size_t)blockIdx.x * 32 + (tid >> 3);
    const int r = tid & 7;
    const bf16* hp = h + row * 512;
    float acc = 0.f;
    #pragma unroll 4
    for (int k8 = 0; k8 < 64; k8++) {
        bf16x8 hv = *(const bf16x8*)&hp[k8 * 8];
        #pragma unroll
        for (int j = 0; j < 8; j++)
            acc += (float)hv[j] * WaL[(k8 * 8 + j) * 8 + r];
    }
    A[row * 8 + r] = acc;
}

// ---------------------------------------------------------------------------
// per-segment: softmax over L for 8 cols + penalty contribution
// ---------------------------------------------------------------------------
__global__ __launch_bounds__(256)
void seg_softmax(const float* __restrict__ A, float* __restrict__ Asg,
                 float* __restrict__ pen)
{
    __shared__ float AsL[1024 * 8];
    __shared__ float red[256];
    __shared__ float amax[8], asum[8];
    const int b = blockIdx.x, tid = threadIdx.x;
    const float* Ab = A + (size_t)b * 8192;
    for (int i = tid * 4; i < 8192; i += 1024)
        *(float4*)&AsL[i] = *(const float4*)&Ab[i];
    __syncthreads();
    const int r = tid & 7, chunk = tid >> 3;     // 32 chunks x 32 rows
    float pm = -1e30f;
    for (int l = chunk * 32; l < chunk * 32 + 32; l++) pm = fmaxf(pm, AsL[l * 8 + r]);
    red[tid] = pm;
    __syncthreads();
    if (tid < 8) {
        float m = -1e30f;
        for (int c = 0; c < 32; c++) m = fmaxf(m, red[c * 8 + tid]);
        amax[tid] = m;
    }
    __syncthreads();
    const float mr = amax[r];
    float ps = 0.f;
    for (int l = chunk * 32; l < chunk * 32 + 32; l++) {
        float e = expf(AsL[l * 8 + r] - mr);
        AsL[l * 8 + r] = e;
        ps += e;
    }
    red[tid] = ps;
    __syncthreads();
    if (tid < 8) {
        float s = 0.f;
        for (int c = 0; c < 32; c++) s += red[c * 8 + tid];
        asum[tid] = s;
    }
    __syncthreads();
    const float inv = 1.f / asum[r];
    for (int l = chunk * 32; l < chunk * 32 + 32; l++) AsL[l * 8 + r] *= inv;
    __syncthreads();
    for (int i = tid * 4; i < 8192; i += 1024)
        *(float4*)&Asg[(size_t)b * 8192 + i] = *(const float4*)&AsL[i];
    __syncthreads();
    // penalty: sum_{r,s} ((As^T As)[r,s] - 1)^2 ; 64 pairs x 4 l-chunks
    {
        const int rr = (tid & 63) >> 3, ss = tid & 7, ch = tid >> 6;
        float dot = 0.f;
        for (int l = ch * 256; l < ch * 256 + 256; l++)
            dot += AsL[l * 8 + rr] * AsL[l * 8 + ss];
        red[tid] = dot;
    }
    __syncthreads();
    if (tid < 64) {
        float dsum = red[tid] + red[64 + tid] + red[128 + tid] + red[192 + tid];
        float d = dsum - 1.f;
        red[tid] = d * d;
    }
    __syncthreads();
    if (tid == 0) {
        float s = 0.f;
        for (int i = 0; i < 64; i++) s += red[i];
        atomicAdd(pen, s);
    }
}

// ---------------------------------------------------------------------------
// pooled partials: pp[lc][b][r*512+c] = sum_{l in chunk} As[b,l,r]*h[b,l,c]
// grid (64, 4 col-chunks, 4 l-chunks)
// ---------------------------------------------------------------------------
__global__ __launch_bounds__(256)
void pooled_k(const float* __restrict__ Asg, const bf16* __restrict__ h,
              float* __restrict__ pp)
{
    const int b = blockIdx.x;
    const int cc0 = blockIdx.y * 128;
    const int lc = blockIdx.z;
    const int tid = threadIdx.x;
    const int c = tid & 127, rg = tid >> 7;
    float a0 = 0, a1 = 0, a2 = 0, a3 = 0;
    const float* Asb = Asg + (size_t)b * 8192 + (size_t)lc * 256 * 8 + rg * 4;
    const bf16* hb = h + ((size_t)b * 1024 + lc * 256) * 512 + cc0 + c;
    for (int l = 0; l < 256; l++) {
        float4 a = *(const float4*)&Asb[(size_t)l * 8];
        float hv = (float)hb[(size_t)l * 512];
        a0 += a.x * hv; a1 += a.y * hv; a2 += a.z * hv; a3 += a.w * hv;
    }
    float* pb = pp + ((size_t)lc * 64 + b) * 4096 + (rg * 4) * 512 + cc0 + c;
    pb[0] = a0; pb[512] = a1; pb[1024] = a2; pb[1536] = a3;
}

// ---------------------------------------------------------------------------
// per-segment mean/std of x — pass 1: partial sums over 64-row l-chunks
// grid (64, 16)
// ---------------------------------------------------------------------------
__global__ __launch_bounds__(256)
void seg_stats1(const float* __restrict__ x, float* __restrict__ p1,
                float* __restrict__ p2)
{
    const int b = blockIdx.x, lc = blockIdx.y, d = threadIdx.x;
    const float* xb = x + ((size_t)b * 1024 + lc * 64) * 256 + d;
    float s = 0.f, s2 = 0.f;
    #pragma unroll 4
    for (int l = 0; l < 64; l++) {
        float v = xb[(size_t)l * 256];
        s += v; s2 += v * v;
    }
    p1[((size_t)lc * 64 + b) * 256 + d] = s;
    p2[((size_t)lc * 64 + b) * 256 + d] = s2;
}

__global__ __launch_bounds__(256)
void seg_stats2(const float* __restrict__ p1, const float* __restrict__ p2,
                float* __restrict__ mean, float* __restrict__ stdv)
{
    const int b = blockIdx.x, d = threadIdx.x;
    float s = 0.f, s2 = 0.f;
    #pragma unroll
    for (int lc = 0; lc < 16; lc++) {
        s  += p1[((size_t)lc * 64 + b) * 256 + d];
        s2 += p2[((size_t)lc * 64 + b) * 256 + d];
    }
    float m = s * (1.f / 1024.f);
    float var = (s2 - s * m) * (1.f / 1023.f);
    mean[b * 256 + d] = m;
    stdv[b * 256 + d] = sqrtf(fmaxf(var, 0.f));
}

// ---------------------------------------------------------------------------
// head pass 1: z[b][c] += feat[b, kc*512 : kc*512+512] @ Wo1-slice
// grid (64, 9); kc<8 reads pooled partials (summing 4 l-chunks), kc==8 mean/std
// ---------------------------------------------------------------------------
__global__ __launch_bounds__(128)
void head1(const float* __restrict__ pp, const float* __restrict__ mn,
           const float* __restrict__ sd, const float* __restrict__ Wo1,
           float* __restrict__ zbuf)
{
    __shared__ float f[512];
    const int b = blockIdx.x, kc = blockIdx.y, tid = threadIdx.x;
    if (kc < 8) {
        for (int j = tid; j < 512; j += 128) {
            const size_t i = (size_t)kc * 512 + j;
            float s = 0.f;
            #pragma unroll
            for (int lc = 0; lc < 4; lc++)
                s += pp[((size_t)lc * 64 + b) * 4096 + i];
            f[j] = s;
        }
    } else {
        for (int j = tid; j < 256; j += 128) {
            f[j]       = mn[b * 256 + j];
            f[256 + j] = sd[b * 256 + j];
        }
    }
    __syncthreads();
    const float* Wp = Wo1 + (size_t)kc * 512 * 128 + tid;
    float z = 0.f;
    #pragma unroll 8
    for (int j = 0; j < 512; j++) z += f[j] * Wp[(size_t)j * 128];
    atomicAdd(&zbuf[b * 128 + tid], z);
}

// ---------------------------------------------------------------------------
// head pass 2: BN+relu -> @ Wo2 -> log_softmax; b==0 also writes penalty
// ---------------------------------------------------------------------------
__global__ __launch_bounds__(128)
void head2(const float* __restrict__ zbuf, const float* __restrict__ bo1,
           const float* __restrict__ go, const float* __restrict__ beo,
           const float* __restrict__ mo, const float* __restrict__ vo,
           const float* __restrict__ Wo2, const float* __restrict__ bo2,
           const float* __restrict__ pen, float* __restrict__ out)
{
    __shared__ float o[128];
    __shared__ float lg[4];
    const int b = blockIdx.x, tid = threadIdx.x;
    float z = zbuf[b * 128 + tid];
    float s = go[tid] * rsqrtf(vo[tid] + EPS);
    float t = (bo1[tid] - mo[tid]) * s + beo[tid];
    float ov = z * s + t;
    o[tid] = ov > 0.f ? ov : 0.f;
    __syncthreads();
    if (tid < 4) {
        float acc = bo2[tid];
        for (int j = 0; j < 128; j++) acc += o[j] * Wo2[j * 4 + tid];
        lg[tid] = acc;
    }
    __syncthreads();
    if (tid == 0) {
        float m = fmaxf(fmaxf(lg[0], lg[1]), fmaxf(lg[2], lg[3]));
        float sum = 0.f;
        for (int k = 0; k < 4; k++) sum += expf(lg[k] - m);
        float lse = m + logf(sum);
        for (int k = 0; k < 4; k++) out[b * 4 + k] = lg[k] - lse;
        if (b == 0) out[256] = pen[0];
    }
}

// ---------------------------------------------------------------------------
extern "C" void kernel_launch(void* const* d_in, const int* in_sizes, int n_in,
                              void* d_out, int out_size, void* d_ws, size_t ws_size,
                              hipStream_t stream)
{
    const float* x   = (const float*)d_in[0];
    const float* Wa  = (const float*)d_in[2];
    const float* Wo1 = (const float*)d_in[3];
    const float* bo1 = (const float*)d_in[4];
    const float* go  = (const float*)d_in[5];
    const float* beo = (const float*)d_in[6];
    const float* mo  = (const float*)d_in[7];
    const float* vo  = (const float*)d_in[8];
    const float* Wo2 = (const float*)d_in[9];
    const float* bo2 = (const float*)d_in[10];
    const float *W[4], *bb[4], *gg[4], *be[4], *mm[4], *vv[4];
    for (int l = 0; l < 4; l++) {
        W[l]  = (const float*)d_in[11 + 6 * l + 0];
        bb[l] = (const float*)d_in[11 + 6 * l + 1];
        gg[l] = (const float*)d_in[11 + 6 * l + 2];
        be[l] = (const float*)d_in[11 + 6 * l + 3];
        mm[l] = (const float*)d_in[11 + 6 * l + 4];
        vv[l] = (const float*)d_in[11 + 6 * l + 5];
    }

    char* w = (char*)d_ws;
    bf16* xb  = (bf16*)w;  w += (size_t)65536 * 256 * 2;   // 32 MB
    bf16* hA  = (bf16*)w;  w += (size_t)65536 * 512 * 2;   // 64 MB
    bf16* hB  = (bf16*)w;  w += (size_t)65536 * 512 * 2;   // 64 MB
    bf16* w1t = (bf16*)w;  w += (size_t)512 * 256 * 2;
    bf16* w2t = (bf16*)w;  w += (size_t)512 * 512 * 2;
    bf16* w3t = (bf16*)w;  w += (size_t)512 * 512 * 2;
    bf16* w4t = (bf16*)w;  w += (size_t)512 * 512 * 2;
    float* sb = (float*)w; w += (size_t)4 * 1024 * 4;      // [layer][s|t][512]
    float* Ab = (float*)w; w += (size_t)65536 * 8 * 4;
    float* As = (float*)w; w += (size_t)65536 * 8 * 4;
    float* pp = (float*)w; w += (size_t)4 * 64 * 4096 * 4; // pooled partials
    float* p1 = (float*)w; w += (size_t)16 * 64 * 256 * 4;
    float* p2 = (float*)w; w += (size_t)16 * 64 * 256 * 4;
    float* mn = (float*)w; w += (size_t)64 * 256 * 4;
    float* sd = (float*)w; w += (size_t)64 * 256 * 4;
    float* zbuf = (float*)w; w += (size_t)64 * 128 * 4;
    float* pen = (float*)w;

    hipMemsetAsync(zbuf, 0, (64 * 128 + 1) * sizeof(float), stream); // zbuf + pen

    convert_x<<<16384, 256, 0, stream>>>(x, xb);
    transpose_w<256><<<512, 256, 0, stream>>>(W[0], w1t);
    transpose_w<512><<<1024, 256, 0, stream>>>(W[1], w2t);
    transpose_w<512><<<1024, 256, 0, stream>>>(W[2], w3t);
    transpose_w<512><<<1024, 256, 0, stream>>>(W[3], w4t);
    for (int l = 0; l < 4; l++)
        scalebias<<<2, 256, 0, stream>>>(bb[l], gg[l], be[l], mm[l], vv[l],
                                         sb + l * 1024, sb + l * 1024 + 512);
    seg_stats1<<<dim3(64, 16), 256, 0, stream>>>(x, p1, p2);
    seg_stats2<<<64, 256, 0, stream>>>(p1, p2, mn, sd);

    gemm_bt<256><<<dim3(512, 4), 256, 0, stream>>>(xb, w1t, sb + 0,    sb + 512,  hA);
    gemm_bt<512><<<dim3(512, 4), 256, 0, stream>>>(hA, w2t, sb + 1024, sb + 1536, hB);
    gemm_bt<512><<<dim3(512, 4), 256, 0, stream>>>(hB, w3t, sb + 2048, sb + 2560, hA);
    gemm_bt<512><<<dim3(512, 4), 256, 0, stream>>>(hA, w4t, sb + 3072, sb + 3584, hB);

    compute_A<<<2048, 256, 0, stream>>>(hB, Wa, Ab);
    seg_softmax<<<64, 256, 0, stream>>>(Ab, As, pen);
    pooled_k<<<dim3(64, 4, 4), 256, 0, stream>>>(As, hB, pp);
    head1<<<dim3(64, 9), 128, 0, stream>>>(pp, mn, sd, Wo1, zbuf);
    head2<<<64, 128, 0, stream>>>(zbuf, bo1, go, beo, mo, vo, Wo2, bo2,
                                  pen, (float*)d_out);
}

// Round 3
// 523.482 us; speedup vs baseline: 1.4537x; 1.0073x over previous
//
#include <hip/hip_runtime.h>
#include <cstdint>
#include <cstddef>

typedef __bf16 bf16;
typedef __bf16 bf16x4 __attribute__((ext_vector_type(4)));
typedef __bf16 bf16x8 __attribute__((ext_vector_type(8)));
typedef float  f32x4  __attribute__((ext_vector_type(4)));
typedef unsigned int uint;

#define EPS 1e-5f

// ---------------------------------------------------------------------------
// async global->LDS, 16B per lane. LDS dest is wave-uniform base + lane*16.
// ---------------------------------------------------------------------------
__device__ __forceinline__ void load_lds16(const void* g, void* l) {
    typedef __attribute__((address_space(1))) void gvoid;
    typedef __attribute__((address_space(3))) void lvoid;
    gvoid* gp = (gvoid*)(unsigned long long)(uintptr_t)g;
    lvoid* lp = (lvoid*)(unsigned int)(uintptr_t)l;
    __builtin_amdgcn_global_load_lds(gp, lp, 16, 0, 0);
}

// ---------------------------------------------------------------------------
// fused: x -> bf16 copy + per-(b,d) partial sums for mean/std. grid (64,16)
// ---------------------------------------------------------------------------
__global__ __launch_bounds__(256)
void convert_stats(const float* __restrict__ x, bf16* __restrict__ xb,
                   float* __restrict__ p1, float* __restrict__ p2)
{
    const int b = blockIdx.x, lc = blockIdx.y, d = threadIdx.x;
    const size_t base = ((size_t)b * 1024 + lc * 64) * 256;
    float s = 0.f, s2 = 0.f;
    #pragma unroll 4
    for (int l = 0; l < 64; l++) {
        float v = x[base + (size_t)l * 256 + d];
        xb[base + (size_t)l * 256 + d] = (bf16)v;
        s += v; s2 += v * v;
    }
    p1[((size_t)lc * 64 + b) * 256 + d] = s;
    p2[((size_t)lc * 64 + b) * 256 + d] = s2;
}

__global__ __launch_bounds__(256)
void seg_stats2(const float* __restrict__ p1, const float* __restrict__ p2,
                float* __restrict__ mean, float* __restrict__ stdv)
{
    const int b = blockIdx.x, d = threadIdx.x;
    float s = 0.f, s2 = 0.f;
    #pragma unroll
    for (int lc = 0; lc < 16; lc++) {
        s  += p1[((size_t)lc * 64 + b) * 256 + d];
        s2 += p2[((size_t)lc * 64 + b) * 256 + d];
    }
    float m = s * (1.f / 1024.f);
    float var = (s2 - s * m) * (1.f / 1023.f);
    mean[b * 256 + d] = m;
    stdv[b * 256 + d] = sqrtf(fmaxf(var, 0.f));
}

// ---------------------------------------------------------------------------
// weight prep
// ---------------------------------------------------------------------------
__global__ void transpose_w256(const float* __restrict__ W, bf16* __restrict__ Wt) {
    int idx = blockIdx.x * 256 + threadIdx.x;     // 512*256
    int n = idx >> 8, k = idx & 255;
    Wt[idx] = (bf16)W[k * 512 + n];
}

__global__ void transpose_w512x3(const float* __restrict__ W2, const float* __restrict__ W3,
                                 const float* __restrict__ W4, bf16* __restrict__ t2,
                                 bf16* __restrict__ t3, bf16* __restrict__ t4)
{
    const float* W = blockIdx.y == 0 ? W2 : (blockIdx.y == 1 ? W3 : W4);
    bf16* Wt       = blockIdx.y == 0 ? t2 : (blockIdx.y == 1 ? t3 : t4);
    int idx = blockIdx.x * 256 + threadIdx.x;     // 512*512
    int n = idx >> 9, k = idx & 511;
    Wt[idx] = (bf16)W[k * 512 + n];
}

__global__ void scalebias_all(
    const float* b1, const float* g1, const float* be1, const float* m1, const float* v1,
    const float* b2, const float* g2, const float* be2, const float* m2, const float* v2,
    const float* b3, const float* g3, const float* be3, const float* m3, const float* v3,
    const float* b4, const float* g4, const float* be4, const float* m4, const float* v4,
    float* __restrict__ sb)
{
    const int lay = blockIdx.x >> 1;
    const int j = (blockIdx.x & 1) * 256 + threadIdx.x;
    const float *b, *g, *be, *m, *v;
    switch (lay) {
        case 0: b=b1; g=g1; be=be1; m=m1; v=v1; break;
        case 1: b=b2; g=g2; be=be2; m=m2; v=v2; break;
        case 2: b=b3; g=g3; be=be3; m=m3; v=v3; break;
        default:b=b4; g=g4; be=be4; m=m4; v=v4; break;
    }
    float sj = g[j] * rsqrtf(v[j] + EPS);
    sb[lay * 1024 + j]       = sj;
    sb[lay * 1024 + 512 + j] = (b[j] - m[j]) * sj + be[j];
}

// ---------------------------------------------------------------------------
// m97-structure GEMM: C[M,512] = relu( (A[M,K] @ Wt[512,K]^T) * s + t ), bf16 out
// 128x128 tile, BK=32, 4 waves (2x2), coalesced LDS-bounce epilogue
// ---------------------------------------------------------------------------
template<int K>
__global__ __launch_bounds__(256, 4)
void gemm_bt(const bf16* __restrict__ A, const bf16* __restrict__ Bt,
             const float* __restrict__ sc, const float* __restrict__ bi,
             bf16* __restrict__ C)
{
    __shared__ __align__(16) char smem[32768];
    bf16* As = (bf16*)smem;
    bf16* Bs = (bf16*)(smem + 16384);

    const int tid  = threadIdx.x;
    const int lane = tid & 63;
    const int wid  = tid >> 6;
    const int wm   = wid >> 1;
    const int wn   = wid & 1;
    const size_t m0 = (size_t)blockIdx.x * 128;
    const int    n0 = blockIdx.y * 128;

    const int r0 = tid >> 2;
    const int cc = tid & 3;

    bf16* AsW0 = &As[((tid & 192)      ) * 8];
    bf16* AsW1 = &As[((tid & 192) + 256) * 8];
    bf16* BsW0 = &Bs[((tid & 192)      ) * 8];
    bf16* BsW1 = &Bs[((tid & 192) + 256) * 8];

    f32x4 acc[4][4] = {};
    const int quad = lane >> 4;
    const int l16  = lane & 15;

    for (int k0 = 0; k0 < K; k0 += 32) {
        load_lds16(&A [(m0 +       r0) * K + k0 + cc * 8], AsW0);
        load_lds16(&A [(m0 + 64 +  r0) * K + k0 + cc * 8], AsW1);
        load_lds16(&Bt[(size_t)(n0 +      r0) * K + k0 + cc * 8], BsW0);
        load_lds16(&Bt[(size_t)(n0 + 64 + r0) * K + k0 + cc * 8], BsW1);
        __syncthreads();

        bf16x8 af[4], bfr[4];
        #pragma unroll
        for (int i = 0; i < 4; i++)
            af[i] = *(const bf16x8*)&As[(wm * 64 + i * 16 + l16) * 32 + quad * 8];
        #pragma unroll
        for (int j = 0; j < 4; j++)
            bfr[j] = *(const bf16x8*)&Bs[(wn * 64 + j * 16 + l16) * 32 + quad * 8];
        #pragma unroll
        for (int i = 0; i < 4; i++)
            #pragma unroll
            for (int j = 0; j < 4; j++)
                acc[i][j] = __builtin_amdgcn_mfma_f32_16x16x32_bf16(af[i], bfr[j], acc[i][j], 0, 0, 0);
        __syncthreads();
    }

    // ---- epilogue: scale+bias+relu, pack pairs, bounce through LDS, store 16B
    // per-wave LDS region: 64 rows x 32 dwords (128B), 16B-chunk XOR swizzle
    uint* Ep = (uint*)smem + wid * 2048;
    const bool evenlane = (lane & 1) == 0;
    #pragma unroll
    for (int j = 0; j < 4; j++) {
        const int col = n0 + wn * 64 + j * 16 + l16;
        const float s = sc[col], t = bi[col];
        #pragma unroll
        for (int i = 0; i < 4; i++) {
            #pragma unroll
            for (int r = 0; r < 4; r++) {
                float v = acc[i][j][r] * s + t;
                v = v > 0.f ? v : 0.f;
                float pv = __shfl_xor(v, 1, 64);   // partner col (l16^1)
                if (evenlane) {
                    bf16 a = (bf16)v, b = (bf16)pv;
                    uint pk = (uint)*(unsigned short*)&a |
                              ((uint)*(unsigned short*)&b << 16);
                    const int row_l = i * 16 + quad * 4 + r;
                    const int c2 = j * 8 + (l16 >> 1);          // dword col 0..31
                    const int chunk = c2 >> 2, pos = c2 & 3;
                    Ep[row_l * 32 + ((chunk ^ (row_l & 7)) << 2) + pos] = pk;
                }
            }
        }
    }
    // same-wave read-back (no barrier needed), fully coalesced 128B stores
    const int r8 = lane >> 3, l8 = lane & 7;
    #pragma unroll
    for (int it = 0; it < 8; it++) {
        const int row_l = it * 8 + r8;
        const int chunk = l8 ^ (row_l & 7);
        uint4 val = *(uint4*)&Ep[row_l * 32 + chunk * 4];
        const size_t row_g = m0 + wm * 64 + row_l;
        const int    col_g = n0 + wn * 64 + l8 * 8;
        *(uint4*)&C[row_g * 512 + col_g] = val;
    }
}

// ---------------------------------------------------------------------------
// A[N,8] = h4[N,512](bf16) @ Wa[512,8](f32)
// ---------------------------------------------------------------------------
__global__ __launch_bounds__(256)
void compute_A(const bf16* __restrict__ h, const float* __restrict__ Wa,
               float* __restrict__ A)
{
    __shared__ float WaL[512 * 8];
    const int tid = threadIdx.x;
    for (int i = tid; i < 4096; i += 256) WaL[i] = Wa[i];
    __syncthreads();
    const size_t row = (size_t)blockIdx.x * 32 + (tid >> 3);
    const int r = tid & 7;
    const bf16* hp = h + row * 512;
    float acc0 = 0.f, acc1 = 0.f;
    #pragma unroll 4
    for (int k8 = 0; k8 < 64; k8 += 2) {
        bf16x8 h0 = *(const bf16x8*)&hp[k8 * 8];
        bf16x8 h1 = *(const bf16x8*)&hp[k8 * 8 + 8];
        #pragma unroll
        for (int j = 0; j < 8; j++) {
            acc0 += (float)h0[j] * WaL[(k8 * 8 + j) * 8 + r];
            acc1 += (float)h1[j] * WaL[(k8 * 8 + 8 + j) * 8 + r];
        }
    }
    A[row * 8 + r] = acc0 + acc1;
}

// ---------------------------------------------------------------------------
// per-segment softmax over L (8 cols) + penalty. 1024 threads.
// ---------------------------------------------------------------------------
__global__ __launch_bounds__(1024)
void seg_softmax(const float* __restrict__ A, float* __restrict__ Asg,
                 float* __restrict__ pen)
{
    __shared__ float AsL[8192];
    __shared__ float red[1024];
    __shared__ float amax[8], asum[8];
    const int b = blockIdx.x, tid = threadIdx.x;
    const float* Ab = A + (size_t)b * 8192;
    for (int i = tid * 4; i < 8192; i += 4096)
        *(float4*)&AsL[i] = *(const float4*)&Ab[i];
    __syncthreads();
    const int r = tid & 7, chunk = tid >> 3;      // 128 chunks x 8 rows
    float pm = -1e30f;
    for (int l = chunk * 8; l < chunk * 8 + 8; l++) pm = fmaxf(pm, AsL[l * 8 + r]);
    red[tid] = pm;
    __syncthreads();
    if (tid < 512) red[tid] = fmaxf(red[tid], red[tid + 512]); __syncthreads();
    if (tid < 256) red[tid] = fmaxf(red[tid], red[tid + 256]); __syncthreads();
    if (tid < 128) red[tid] = fmaxf(red[tid], red[tid + 128]); __syncthreads();
    if (tid <  64) red[tid] = fmaxf(red[tid], red[tid +  64]); __syncthreads();
    if (tid <  32) red[tid] = fmaxf(red[tid], red[tid +  32]); __syncthreads();
    if (tid <  16) red[tid] = fmaxf(red[tid], red[tid +  16]); __syncthreads();
    if (tid <   8) amax[tid] = fmaxf(red[tid], red[tid + 8]);  __syncthreads();
    const float mr = amax[r];
    float ps = 0.f;
    for (int l = chunk * 8; l < chunk * 8 + 8; l++) {
        float e = expf(AsL[l * 8 + r] - mr);
        AsL[l * 8 + r] = e;
        ps += e;
    }
    red[tid] = ps;
    __syncthreads();
    if (tid < 512) red[tid] += red[tid + 512]; __syncthreads();
    if (tid < 256) red[tid] += red[tid + 256]; __syncthreads();
    if (tid < 128) red[tid] += red[tid + 128]; __syncthreads();
    if (tid <  64) red[tid] += red[tid +  64]; __syncthreads();
    if (tid <  32) red[tid] += red[tid +  32]; __syncthreads();
    if (tid <  16) red[tid] += red[tid +  16]; __syncthreads();
    if (tid <   8) asum[tid] = red[tid] + red[tid + 8];        __syncthreads();
    const float inv = 1.f / asum[r];
    for (int l = chunk * 8; l < chunk * 8 + 8; l++) AsL[l * 8 + r] *= inv;
    __syncthreads();
    for (int i = tid * 4; i < 8192; i += 4096)
        *(float4*)&Asg[(size_t)b * 8192 + i] = *(const float4*)&AsL[i];
    __syncthreads();
    // penalty: 64 (rr,ss) pairs x 16 l-chunks of 64
    {
        const int p = tid & 63, ch = tid >> 6;
        const int rr = p >> 3, ss = p & 7;
        float dot = 0.f;
        for (int l = ch * 64; l < ch * 64 + 64; l++)
            dot += AsL[l * 8 + rr] * AsL[l * 8 + ss];
        red[tid] = dot;
    }
    __syncthreads();
    if (tid < 512) red[tid] += red[tid + 512]; __syncthreads();
    if (tid < 256) red[tid] += red[tid + 256]; __syncthreads();
    if (tid < 128) red[tid] += red[tid + 128]; __syncthreads();
    if (tid < 64) {
        float d = red[tid] + red[tid + 64] - 1.f;
        red[tid] = d * d;
    }
    __syncthreads();
    if (tid == 0) {
        float s = 0.f;
        for (int i = 0; i < 64; i++) s += red[i];
        atomicAdd(pen, s);
    }
}

// ---------------------------------------------------------------------------
// pooled partials: grid (64, 4 col-chunks, 8 l-chunks of 128)
// ---------------------------------------------------------------------------
__global__ __launch_bounds__(256)
void pooled_k(const float* __restrict__ Asg, const bf16* __restrict__ h,
              float* __restrict__ pp)
{
    const int b = blockIdx.x;
    const int cc0 = blockIdx.y * 128;
    const int lc = blockIdx.z;
    const int tid = threadIdx.x;
    const int c = tid & 127, rg = tid >> 7;
    float a0 = 0, a1 = 0, a2 = 0, a3 = 0;
    const float* Asb = Asg + (size_t)b * 8192 + (size_t)lc * 128 * 8 + rg * 4;
    const bf16* hb = h + ((size_t)b * 1024 + lc * 128) * 512 + cc0 + c;
    #pragma unroll 4
    for (int l = 0; l < 128; l++) {
        float4 a = *(const float4*)&Asb[(size_t)l * 8];
        float hv = (float)hb[(size_t)l * 512];
        a0 += a.x * hv; a1 += a.y * hv; a2 += a.z * hv; a3 += a.w * hv;
    }
    float* pb = pp + ((size_t)lc * 64 + b) * 4096 + (rg * 4) * 512 + cc0 + c;
    pb[0] = a0; pb[512] = a1; pb[1024] = a2; pb[1536] = a3;
}

// ---------------------------------------------------------------------------
// head pass 1: z[b][c] += feat-chunk @ Wo1-slice. grid (64, 9)
// ---------------------------------------------------------------------------
__global__ __launch_bounds__(128)
void head1(const float* __restrict__ pp, const float* __restrict__ mn,
           const float* __restrict__ sd, const float* __restrict__ Wo1,
           float* __restrict__ zbuf)
{
    __shared__ float f[512];
    const int b = blockIdx.x, kc = blockIdx.y, tid = threadIdx.x;
    if (kc < 8) {
        for (int j = tid; j < 512; j += 128) {
            const size_t i = (size_t)kc * 512 + j;
            float s = 0.f;
            #pragma unroll
            for (int lc = 0; lc < 8; lc++)
                s += pp[((size_t)lc * 64 + b) * 4096 + i];
            f[j] = s;
        }
    } else {
        for (int j = tid; j < 256; j += 128) {
            f[j]       = mn[b * 256 + j];
            f[256 + j] = sd[b * 256 + j];
        }
    }
    __syncthreads();
    const float* Wp = Wo1 + (size_t)kc * 512 * 128 + tid;
    float z = 0.f;
    #pragma unroll 8
    for (int j = 0; j < 512; j++) z += f[j] * Wp[(size_t)j * 128];
    atomicAdd(&zbuf[b * 128 + tid], z);
}

// ---------------------------------------------------------------------------
// head pass 2: BN+relu -> @ Wo2 -> log_softmax; b==0 writes penalty
// ---------------------------------------------------------------------------
__global__ __launch_bounds__(128)
void head2(const float* __restrict__ zbuf, const float* __restrict__ bo1,
           const float* __restrict__ go, const float* __restrict__ beo,
           const float* __restrict__ mo, const float* __restrict__ vo,
           const float* __restrict__ Wo2, const float* __restrict__ bo2,
           const float* __restrict__ pen, float* __restrict__ out)
{
    __shared__ float o[128];
    __shared__ float lg[4];
    const int b = blockIdx.x, tid = threadIdx.x;
    float z = zbuf[b * 128 + tid];
    float s = go[tid] * rsqrtf(vo[tid] + EPS);
    float t = (bo1[tid] - mo[tid]) * s + beo[tid];
    float ov = z * s + t;
    o[tid] = ov > 0.f ? ov : 0.f;
    __syncthreads();
    if (tid < 4) {
        float acc = bo2[tid];
        for (int j = 0; j < 128; j++) acc += o[j] * Wo2[j * 4 + tid];
        lg[tid] = acc;
    }
    __syncthreads();
    if (tid == 0) {
        float m = fmaxf(fmaxf(lg[0], lg[1]), fmaxf(lg[2], lg[3]));
        float sum = 0.f;
        for (int k = 0; k < 4; k++) sum += expf(lg[k] - m);
        float lse = m + logf(sum);
        for (int k = 0; k < 4; k++) out[b * 4 + k] = lg[k] - lse;
        if (b == 0) out[256] = pen[0];
    }
}

// ---------------------------------------------------------------------------
extern "C" void kernel_launch(void* const* d_in, const int* in_sizes, int n_in,
                              void* d_out, int out_size, void* d_ws, size_t ws_size,
                              hipStream_t stream)
{
    const float* x   = (const float*)d_in[0];
    const float* Wa  = (const float*)d_in[2];
    const float* Wo1 = (const float*)d_in[3];
    const float* bo1 = (const float*)d_in[4];
    const float* go  = (const float*)d_in[5];
    const float* beo = (const float*)d_in[6];
    const float* mo  = (const float*)d_in[7];
    const float* vo  = (const float*)d_in[8];
    const float* Wo2 = (const float*)d_in[9];
    const float* bo2 = (const float*)d_in[10];
    const float *W[4], *bb[4], *gg[4], *be[4], *mm[4], *vv[4];
    for (int l = 0; l < 4; l++) {
        W[l]  = (const float*)d_in[11 + 6 * l + 0];
        bb[l] = (const float*)d_in[11 + 6 * l + 1];
        gg[l] = (const float*)d_in[11 + 6 * l + 2];
        be[l] = (const float*)d_in[11 + 6 * l + 3];
        mm[l] = (const float*)d_in[11 + 6 * l + 4];
        vv[l] = (const float*)d_in[11 + 6 * l + 5];
    }

    char* w = (char*)d_ws;
    bf16* xb  = (bf16*)w;  w += (size_t)65536 * 256 * 2;   // 32 MB
    bf16* hA  = (bf16*)w;  w += (size_t)65536 * 512 * 2;   // 64 MB
    bf16* hB  = (bf16*)w;  w += (size_t)65536 * 512 * 2;   // 64 MB
    bf16* w1t = (bf16*)w;  w += (size_t)512 * 256 * 2;
    bf16* w2t = (bf16*)w;  w += (size_t)512 * 512 * 2;
    bf16* w3t = (bf16*)w;  w += (size_t)512 * 512 * 2;
    bf16* w4t = (bf16*)w;  w += (size_t)512 * 512 * 2;
    float* sb = (float*)w; w += (size_t)4 * 1024 * 4;      // [layer][s|t][512]
    float* Ab = (float*)w; w += (size_t)65536 * 8 * 4;
    float* As = (float*)w; w += (size_t)65536 * 8 * 4;
    float* pp = (float*)w; w += (size_t)8 * 64 * 4096 * 4; // pooled partials
    float* p1 = (float*)w; w += (size_t)16 * 64 * 256 * 4;
    float* p2 = (float*)w; w += (size_t)16 * 64 * 256 * 4;
    float* mn = (float*)w; w += (size_t)64 * 256 * 4;
    float* sd = (float*)w; w += (size_t)64 * 256 * 4;
    float* zbuf = (float*)w; w += (size_t)64 * 128 * 4;
    float* pen = (float*)w;

    hipMemsetAsync(zbuf, 0, (64 * 128 + 1) * sizeof(float), stream); // zbuf + pen

    convert_stats<<<dim3(64, 16), 256, 0, stream>>>(x, xb, p1, p2);
    seg_stats2<<<64, 256, 0, stream>>>(p1, p2, mn, sd);
    transpose_w256<<<512, 256, 0, stream>>>(W[0], w1t);
    transpose_w512x3<<<dim3(1024, 3), 256, 0, stream>>>(W[1], W[2], W[3], w2t, w3t, w4t);
    scalebias_all<<<8, 256, 0, stream>>>(
        bb[0], gg[0], be[0], mm[0], vv[0],
        bb[1], gg[1], be[1], mm[1], vv[1],
        bb[2], gg[2], be[2], mm[2], vv[2],
        bb[3], gg[3], be[3], mm[3], vv[3], sb);

    gemm_bt<256><<<dim3(512, 4), 256, 0, stream>>>(xb, w1t, sb + 0,    sb + 512,  hA);
    gemm_bt<512><<<dim3(512, 4), 256, 0, stream>>>(hA, w2t, sb + 1024, sb + 1536, hB);
    gemm_bt<512><<<dim3(512, 4), 256, 0, stream>>>(hB, w3t, sb + 2048, sb + 2560, hA);
    gemm_bt<512><<<dim3(512, 4), 256, 0, stream>>>(hA, w4t, sb + 3072, sb + 3584, hB);

    compute_A<<<2048, 256, 0, stream>>>(hB, Wa, Ab);
    seg_softmax<<<64, 1024, 0, stream>>>(Ab, As, pen);
    pooled_k<<<dim3(64, 4, 8), 256, 0, stream>>>(As, hB, pp);
    head1<<<dim3(64, 9), 128, 0, stream>>>(pp, mn, sd, Wo1, zbuf);
    head2<<<64, 128, 0, stream>>>(zbuf, bo1, go, beo, mo, vo, Wo2, bo2,
                                  pen, (float*)d_out);
}

// Round 4
// 512.747 us; speedup vs baseline: 1.4842x; 1.0209x over previous
//
#include <hip/hip_runtime.h>
#include <cstdint>
#include <cstddef>

typedef __bf16 bf16;
typedef __bf16 bf16x4 __attribute__((ext_vector_type(4)));
typedef __bf16 bf16x8 __attribute__((ext_vector_type(8)));
typedef float  f32x4  __attribute__((ext_vector_type(4)));
typedef unsigned int uint;

#define EPS 1e-5f

// ---------------------------------------------------------------------------
// async global->LDS, 16B per lane. LDS dest is wave-uniform base + lane*16.
// ---------------------------------------------------------------------------
__device__ __forceinline__ void load_lds16(const void* g, void* l) {
    typedef __attribute__((address_space(1))) void gvoid;
    typedef __attribute__((address_space(3))) void lvoid;
    gvoid* gp = (gvoid*)(unsigned long long)(uintptr_t)g;
    lvoid* lp = (lvoid*)(unsigned int)(uintptr_t)l;
    __builtin_amdgcn_global_load_lds(gp, lp, 16, 0, 0);
}

// ---------------------------------------------------------------------------
// fused: x -> bf16 copy + per-(b,d) partial sums for mean/std. grid (64,16)
// ---------------------------------------------------------------------------
__global__ __launch_bounds__(256)
void convert_stats(const float* __restrict__ x, bf16* __restrict__ xb,
                   float* __restrict__ p1, float* __restrict__ p2)
{
    const int b = blockIdx.x, lc = blockIdx.y, d = threadIdx.x;
    const size_t base = ((size_t)b * 1024 + lc * 64) * 256;
    float s = 0.f, s2 = 0.f;
    #pragma unroll 4
    for (int l = 0; l < 64; l++) {
        float v = x[base + (size_t)l * 256 + d];
        xb[base + (size_t)l * 256 + d] = (bf16)v;
        s += v; s2 += v * v;
    }
    p1[((size_t)lc * 64 + b) * 256 + d] = s;
    p2[((size_t)lc * 64 + b) * 256 + d] = s2;
}

// ---------------------------------------------------------------------------
// all weight prep in ONE dispatch: 4 transposes + 4 scale/bias. 3592 blocks.
// ---------------------------------------------------------------------------
__global__ void prep_all(
    const float* __restrict__ W1, const float* __restrict__ W2,
    const float* __restrict__ W3, const float* __restrict__ W4,
    bf16* __restrict__ t1, bf16* __restrict__ t2,
    bf16* __restrict__ t3, bf16* __restrict__ t4,
    const float* b1, const float* g1, const float* be1, const float* m1, const float* v1,
    const float* b2, const float* g2, const float* be2, const float* m2, const float* v2,
    const float* b3, const float* g3, const float* be3, const float* m3, const float* v3,
    const float* b4, const float* g4, const float* be4, const float* m4, const float* v4,
    float* __restrict__ sb)
{
    const int bid = blockIdx.x, tid = threadIdx.x;
    if (bid < 512) {                       // W1: 512x256 (Wt[n][k])
        int idx = bid * 256 + tid;
        int n = idx >> 8, k = idx & 255;
        t1[idx] = (bf16)W1[k * 512 + n];
    } else if (bid < 3584) {               // W2/W3/W4: 512x512 each
        int r = bid - 512;
        int which = r >> 10;               // 1024 blocks each
        int idx = (r & 1023) * 256 + tid;
        int n = idx >> 9, k = idx & 511;
        const float* W = which == 0 ? W2 : (which == 1 ? W3 : W4);
        bf16* Wt       = which == 0 ? t2 : (which == 1 ? t3 : t4);
        Wt[idx] = (bf16)W[k * 512 + n];
    } else {                               // scale/bias: 8 blocks
        int r = bid - 3584;
        int lay = r >> 1;
        int j = (r & 1) * 256 + tid;
        const float *b, *g, *be, *m, *v;
        switch (lay) {
            case 0: b=b1; g=g1; be=be1; m=m1; v=v1; break;
            case 1: b=b2; g=g2; be=be2; m=m2; v=v2; break;
            case 2: b=b3; g=g3; be=be3; m=m3; v=v3; break;
            default:b=b4; g=g4; be=be4; m=m4; v=v4; break;
        }
        float sj = g[j] * rsqrtf(v[j] + EPS);
        sb[lay * 1024 + j]       = sj;
        sb[lay * 1024 + 512 + j] = (b[j] - m[j]) * sj + be[j];
    }
}

// ---------------------------------------------------------------------------
// GEMM: C[M,512] = relu( (A[M,K] @ Wt[512,K]^T) * s + t ), bf16 out
// 128x128 tile, BK=64 (two BK=32 sub-buffers -> half the barriers),
// coalesced LDS-bounce epilogue. FUSE_A: also emit A-partials tile @ Wa.
// ---------------------------------------------------------------------------
template<int K, bool FUSE_A>
__global__ __launch_bounds__(256, 4)
void gemm_bt(const bf16* __restrict__ A, const bf16* __restrict__ Bt,
             const float* __restrict__ sc, const float* __restrict__ bi,
             bf16* __restrict__ C, const float* __restrict__ Wa,
             float* __restrict__ Apart)
{
    __shared__ __align__(16) char smem[32768];
    __shared__ float WaL[128 * 8];
    bf16* As0 = (bf16*)smem;
    bf16* As1 = (bf16*)(smem + 8192);
    bf16* Bs0 = (bf16*)(smem + 16384);
    bf16* Bs1 = (bf16*)(smem + 24576);

    const int tid  = threadIdx.x;
    const int lane = tid & 63;
    const int wid  = tid >> 6;
    const int wm   = wid >> 1;
    const int wn   = wid & 1;
    const size_t m0 = (size_t)blockIdx.x * 128;
    const int    n0 = blockIdx.y * 128;

    if constexpr (FUSE_A) {
        for (int i = tid; i < 1024; i += 256) WaL[i] = Wa[n0 * 8 + i];
    }

    const int r0 = tid >> 2;               // staging row (round 0)
    const int cc = tid & 3;                // 8-elem chunk within 32-k row
    const int wb0 = (tid & 192) * 8;       // wave-uniform chunk base (elements)
    const int wb1 = ((tid & 192) + 256) * 8;

    f32x4 acc[4][4] = {};
    const int quad = lane >> 4;
    const int l16  = lane & 15;

    for (int k0 = 0; k0 < K; k0 += 64) {
        load_lds16(&A [(m0 +      r0) * K + k0      + cc * 8], As0 + wb0);
        load_lds16(&A [(m0 + 64 + r0) * K + k0      + cc * 8], As0 + wb1);
        load_lds16(&A [(m0 +      r0) * K + k0 + 32 + cc * 8], As1 + wb0);
        load_lds16(&A [(m0 + 64 + r0) * K + k0 + 32 + cc * 8], As1 + wb1);
        load_lds16(&Bt[(size_t)(n0 +      r0) * K + k0      + cc * 8], Bs0 + wb0);
        load_lds16(&Bt[(size_t)(n0 + 64 + r0) * K + k0      + cc * 8], Bs0 + wb1);
        load_lds16(&Bt[(size_t)(n0 +      r0) * K + k0 + 32 + cc * 8], Bs1 + wb0);
        load_lds16(&Bt[(size_t)(n0 + 64 + r0) * K + k0 + 32 + cc * 8], Bs1 + wb1);
        __syncthreads();

        #pragma unroll
        for (int ks = 0; ks < 2; ks++) {
            const bf16* Ak = ks ? As1 : As0;
            const bf16* Bk = ks ? Bs1 : Bs0;
            bf16x8 af[4], bfr[4];
            #pragma unroll
            for (int i = 0; i < 4; i++)
                af[i] = *(const bf16x8*)&Ak[(wm * 64 + i * 16 + l16) * 32 + quad * 8];
            #pragma unroll
            for (int j = 0; j < 4; j++)
                bfr[j] = *(const bf16x8*)&Bk[(wn * 64 + j * 16 + l16) * 32 + quad * 8];
            #pragma unroll
            for (int i = 0; i < 4; i++)
                #pragma unroll
                for (int j = 0; j < 4; j++)
                    acc[i][j] = __builtin_amdgcn_mfma_f32_16x16x32_bf16(af[i], bfr[j], acc[i][j], 0, 0, 0);
        }
        __syncthreads();
    }

    // ---- epilogue: scale+bias+relu, pack pairs, bounce through LDS, store 16B
    uint* Ep = (uint*)smem + wid * 2048;
    const bool evenlane = (lane & 1) == 0;
    #pragma unroll
    for (int j = 0; j < 4; j++) {
        const int col = n0 + wn * 64 + j * 16 + l16;
        const float s = sc[col], t = bi[col];
        #pragma unroll
        for (int i = 0; i < 4; i++) {
            #pragma unroll
            for (int r = 0; r < 4; r++) {
                float v = acc[i][j][r] * s + t;
                v = v > 0.f ? v : 0.f;
                float pv = __shfl_xor(v, 1, 64);   // partner col (l16^1)
                if (evenlane) {
                    bf16 a = (bf16)v, b = (bf16)pv;
                    uint pk = (uint)*(unsigned short*)&a |
                              ((uint)*(unsigned short*)&b << 16);
                    const int row_l = i * 16 + quad * 4 + r;
                    const int c2 = j * 8 + (l16 >> 1);          // dword col 0..31
                    const int chunk = c2 >> 2, pos = c2 & 3;
                    Ep[row_l * 32 + ((chunk ^ (row_l & 7)) << 2) + pos] = pk;
                }
            }
        }
    }
    // same-wave read-back (no barrier needed), fully coalesced 128B stores
    const int r8 = lane >> 3, l8 = lane & 7;
    #pragma unroll
    for (int it = 0; it < 8; it++) {
        const int row_l = it * 8 + r8;
        const int chunk = l8 ^ (row_l & 7);
        uint4 val = *(uint4*)&Ep[row_l * 32 + chunk * 4];
        const size_t row_g = m0 + wm * 64 + row_l;
        const int    col_g = n0 + wn * 64 + l8 * 8;
        *(uint4*)&C[row_g * 512 + col_g] = val;
    }

    if constexpr (FUSE_A) {
        // A-partials: Apart[m0+row][blockIdx.y*8 + r] = sum_col tile[row][col]*Wa[n0+col][r]
        __syncthreads();   // all waves' Ep regions final; WaL visible
        const int row = tid & 127, half = tid >> 7;
        const int row64 = row & 63;
        const int wrow  = (row >> 6) << 1;
        float a[8] = {0.f, 0.f, 0.f, 0.f, 0.f, 0.f, 0.f, 0.f};
        const uint* eb = (const uint*)smem;
        #pragma unroll 4
        for (int dd = 0; dd < 32; dd++) {
            const int d = half * 32 + dd;          // dword col 0..63 (128 cols)
            const int wsrc = wrow | (d >> 5);
            const int dr = d & 31;
            uint pk = eb[wsrc * 2048 + row64 * 32 + (((dr >> 2) ^ (row64 & 7)) << 2) + (dr & 3)];
            float vlo = __uint_as_float((pk & 0xffffu) << 16);
            float vhi = __uint_as_float(pk & 0xffff0000u);
            const int col = d * 2;
            #pragma unroll
            for (int r = 0; r < 8; r++)
                a[r] += vlo * WaL[col * 8 + r] + vhi * WaL[col * 8 + 8 + r];
        }
        __syncthreads();   // done reading Ep; smem free for reduction
        float* red = (float*)smem;                 // 256 x 8 floats
        #pragma unroll
        for (int r = 0; r < 8; r++) red[tid * 8 + r] = a[r];
        __syncthreads();
        if (half == 0) {
            float* dst = &Apart[(m0 + row) * 32 + blockIdx.y * 8];
            #pragma unroll
            for (int r = 0; r < 8; r++)
                dst[r] = a[r] + red[(tid + 128) * 8 + r];
        }
    }
}

// ---------------------------------------------------------------------------
// per-segment softmax over L (8 cols) + penalty. 1024 threads.
// Reads A-partials [N][32] (4 y-groups of 8), sums during load.
// ---------------------------------------------------------------------------
__global__ __launch_bounds__(1024)
void seg_softmax(const float* __restrict__ Apart, float* __restrict__ Asg,
                 float* __restrict__ pen)
{
    __shared__ float AsL[8192];
    __shared__ float red[1024];
    __shared__ float amax[8], asum[8];
    const int b = blockIdx.x, tid = threadIdx.x;
    {
        const float4* ap = (const float4*)&Apart[((size_t)b * 1024 + tid) * 32];
        float4 lo = ap[0], hi = ap[1];
        #pragma unroll
        for (int y = 1; y < 4; y++) {
            float4 l2 = ap[y * 2], h2 = ap[y * 2 + 1];
            lo.x += l2.x; lo.y += l2.y; lo.z += l2.z; lo.w += l2.w;
            hi.x += h2.x; hi.y += h2.y; hi.z += h2.z; hi.w += h2.w;
        }
        *(float4*)&AsL[tid * 8]     = lo;
        *(float4*)&AsL[tid * 8 + 4] = hi;
    }
    __syncthreads();
    const int r = tid & 7, chunk = tid >> 3;      // 128 chunks x 8 rows
    float pm = -1e30f;
    for (int l = chunk * 8; l < chunk * 8 + 8; l++) pm = fmaxf(pm, AsL[l * 8 + r]);
    red[tid] = pm;
    __syncthreads();
    if (tid < 512) red[tid] = fmaxf(red[tid], red[tid + 512]); __syncthreads();
    if (tid < 256) red[tid] = fmaxf(red[tid], red[tid + 256]); __syncthreads();
    if (tid < 128) red[tid] = fmaxf(red[tid], red[tid + 128]); __syncthreads();
    if (tid <  64) red[tid] = fmaxf(red[tid], red[tid +  64]); __syncthreads();
    if (tid <  32) red[tid] = fmaxf(red[tid], red[tid +  32]); __syncthreads();
    if (tid <  16) red[tid] = fmaxf(red[tid], red[tid +  16]); __syncthreads();
    if (tid <   8) amax[tid] = fmaxf(red[tid], red[tid + 8]);  __syncthreads();
    const float mr = amax[r];
    float ps = 0.f;
    for (int l = chunk * 8; l < chunk * 8 + 8; l++) {
        float e = expf(AsL[l * 8 + r] - mr);
        AsL[l * 8 + r] = e;
        ps += e;
    }
    red[tid] = ps;
    __syncthreads();
    if (tid < 512) red[tid] += red[tid + 512]; __syncthreads();
    if (tid < 256) red[tid] += red[tid + 256]; __syncthreads();
    if (tid < 128) red[tid] += red[tid + 128]; __syncthreads();
    if (tid <  64) red[tid] += red[tid +  64]; __syncthreads();
    if (tid <  32) red[tid] += red[tid +  32]; __syncthreads();
    if (tid <  16) red[tid] += red[tid +  16]; __syncthreads();
    if (tid <   8) asum[tid] = red[tid] + red[tid + 8];        __syncthreads();
    const float inv = 1.f / asum[r];
    for (int l = chunk * 8; l < chunk * 8 + 8; l++) AsL[l * 8 + r] *= inv;
    __syncthreads();
    for (int i = tid * 4; i < 8192; i += 4096)
        *(float4*)&Asg[(size_t)b * 8192 + i] = *(const float4*)&AsL[i];
    __syncthreads();
    // penalty: 64 (rr,ss) pairs x 16 l-chunks of 64
    {
        const int p = tid & 63, ch = tid >> 6;
        const int rr = p >> 3, ss = p & 7;
        float dot = 0.f;
        for (int l = ch * 64; l < ch * 64 + 64; l++)
            dot += AsL[l * 8 + rr] * AsL[l * 8 + ss];
        red[tid] = dot;
    }
    __syncthreads();
    if (tid < 512) red[tid] += red[tid + 512]; __syncthreads();
    if (tid < 256) red[tid] += red[tid + 256]; __syncthreads();
    if (tid < 128) red[tid] += red[tid + 128]; __syncthreads();
    if (tid < 64) {
        float d = red[tid] + red[tid + 64] - 1.f;
        red[tid] = d * d;
    }
    __syncthreads();
    if (tid == 0) {
        float s = 0.f;
        for (int i = 0; i < 64; i++) s += red[i];
        atomicAdd(pen, s);
    }
}

// ---------------------------------------------------------------------------
// pooled partials: grid (64, 4 col-chunks, 8 l-chunks of 128)
// ---------------------------------------------------------------------------
__global__ __launch_bounds__(256)
void pooled_k(const float* __restrict__ Asg, const bf16* __restrict__ h,
              float* __restrict__ pp)
{
    const int b = blockIdx.x;
    const int cc0 = blockIdx.y * 128;
    const int lc = blockIdx.z;
    const int tid = threadIdx.x;
    const int c = tid & 127, rg = tid >> 7;
    float a0 = 0, a1 = 0, a2 = 0, a3 = 0;
    const float* Asb = Asg + (size_t)b * 8192 + (size_t)lc * 128 * 8 + rg * 4;
    const bf16* hb = h + ((size_t)b * 1024 + lc * 128) * 512 + cc0 + c;
    #pragma unroll 4
    for (int l = 0; l < 128; l++) {
        float4 a = *(const float4*)&Asb[(size_t)l * 8];
        float hv = (float)hb[(size_t)l * 512];
        a0 += a.x * hv; a1 += a.y * hv; a2 += a.z * hv; a3 += a.w * hv;
    }
    float* pb = pp + ((size_t)lc * 64 + b) * 4096 + (rg * 4) * 512 + cc0 + c;
    pb[0] = a0; pb[512] = a1; pb[1024] = a2; pb[1536] = a3;
}

// ---------------------------------------------------------------------------
// head pass 1: z[b][c] += feat-chunk @ Wo1-slice. grid (64, 9)
// kc==8 computes mean/std inline from the convert_stats partials.
// ---------------------------------------------------------------------------
__global__ __launch_bounds__(128)
void head1(const float* __restrict__ pp, const float* __restrict__ p1,
           const float* __restrict__ p2, const float* __restrict__ Wo1,
           float* __restrict__ zbuf)
{
    __shared__ float f[512];
    const int b = blockIdx.x, kc = blockIdx.y, tid = threadIdx.x;
    if (kc < 8) {
        for (int j = tid; j < 512; j += 128) {
            const size_t i = (size_t)kc * 512 + j;
            float s = 0.f;
            #pragma unroll
            for (int lc = 0; lc < 8; lc++)
                s += pp[((size_t)lc * 64 + b) * 4096 + i];
            f[j] = s;
        }
    } else {
        for (int j = tid; j < 256; j += 128) {
            float s = 0.f, s2 = 0.f;
            #pragma unroll
            for (int lc = 0; lc < 16; lc++) {
                s  += p1[((size_t)lc * 64 + b) * 256 + j];
                s2 += p2[((size_t)lc * 64 + b) * 256 + j];
            }
            float m = s * (1.f / 1024.f);
            float var = (s2 - s * m) * (1.f / 1023.f);
            f[j]       = m;
            f[256 + j] = sqrtf(fmaxf(var, 0.f));
        }
    }
    __syncthreads();
    const float* Wp = Wo1 + (size_t)kc * 512 * 128 + tid;
    float z = 0.f;
    #pragma unroll 8
    for (int j = 0; j < 512; j++) z += f[j] * Wp[(size_t)j * 128];
    atomicAdd(&zbuf[b * 128 + tid], z);
}

// ---------------------------------------------------------------------------
// head pass 2: BN+relu -> @ Wo2 -> log_softmax; b==0 writes penalty
// ---------------------------------------------------------------------------
__global__ __launch_bounds__(128)
void head2(const float* __restrict__ zbuf, const float* __restrict__ bo1,
           const float* __restrict__ go, const float* __restrict__ beo,
           const float* __restrict__ mo, const float* __restrict__ vo,
           const float* __restrict__ Wo2, const float* __restrict__ bo2,
           const float* __restrict__ pen, float* __restrict__ out)
{
    __shared__ float o[128];
    __shared__ float lg[4];
    const int b = blockIdx.x, tid = threadIdx.x;
    float z = zbuf[b * 128 + tid];
    float s = go[tid] * rsqrtf(vo[tid] + EPS);
    float t = (bo1[tid] - mo[tid]) * s + beo[tid];
    float ov = z * s + t;
    o[tid] = ov > 0.f ? ov : 0.f;
    __syncthreads();
    if (tid < 4) {
        float acc = bo2[tid];
        for (int j = 0; j < 128; j++) acc += o[j] * Wo2[j * 4 + tid];
        lg[tid] = acc;
    }
    __syncthreads();
    if (tid == 0) {
        float m = fmaxf(fmaxf(lg[0], lg[1]), fmaxf(lg[2], lg[3]));
        float sum = 0.f;
        for (int k = 0; k < 4; k++) sum += expf(lg[k] - m);
        float lse = m + logf(sum);
        for (int k = 0; k < 4; k++) out[b * 4 + k] = lg[k] - lse;
        if (b == 0) out[256] = pen[0];
    }
}

// ---------------------------------------------------------------------------
extern "C" void kernel_launch(void* const* d_in, const int* in_sizes, int n_in,
                              void* d_out, int out_size, void* d_ws, size_t ws_size,
                              hipStream_t stream)
{
    const float* x   = (const float*)d_in[0];
    const float* Wa  = (const float*)d_in[2];
    const float* Wo1 = (const float*)d_in[3];
    const float* bo1 = (const float*)d_in[4];
    const float* go  = (const float*)d_in[5];
    const float* beo = (const float*)d_in[6];
    const float* mo  = (const float*)d_in[7];
    const float* vo  = (const float*)d_in[8];
    const float* Wo2 = (const float*)d_in[9];
    const float* bo2 = (const float*)d_in[10];
    const float *W[4], *bb[4], *gg[4], *be[4], *mm[4], *vv[4];
    for (int l = 0; l < 4; l++) {
        W[l]  = (const float*)d_in[11 + 6 * l + 0];
        bb[l] = (const float*)d_in[11 + 6 * l + 1];
        gg[l] = (const float*)d_in[11 + 6 * l + 2];
        be[l] = (const float*)d_in[11 + 6 * l + 3];
        mm[l] = (const float*)d_in[11 + 6 * l + 4];
        vv[l] = (const float*)d_in[11 + 6 * l + 5];
    }

    char* w = (char*)d_ws;
    bf16* xb  = (bf16*)w;  w += (size_t)65536 * 256 * 2;   // 32 MB
    bf16* hA  = (bf16*)w;  w += (size_t)65536 * 512 * 2;   // 64 MB
    bf16* hB  = (bf16*)w;  w += (size_t)65536 * 512 * 2;   // 64 MB
    bf16* w1t = (bf16*)w;  w += (size_t)512 * 256 * 2;
    bf16* w2t = (bf16*)w;  w += (size_t)512 * 512 * 2;
    bf16* w3t = (bf16*)w;  w += (size_t)512 * 512 * 2;
    bf16* w4t = (bf16*)w;  w += (size_t)512 * 512 * 2;
    float* sb = (float*)w; w += (size_t)4 * 1024 * 4;      // [layer][s|t][512]
    float* Apart = (float*)w; w += (size_t)65536 * 32 * 4; // A-partials [N][32]
    float* As = (float*)w; w += (size_t)65536 * 8 * 4;
    float* pp = (float*)w; w += (size_t)8 * 64 * 4096 * 4; // pooled partials
    float* p1 = (float*)w; w += (size_t)16 * 64 * 256 * 4;
    float* p2 = (float*)w; w += (size_t)16 * 64 * 256 * 4;
    float* zbuf = (float*)w; w += (size_t)64 * 128 * 4;
    float* pen = (float*)w;

    hipMemsetAsync(zbuf, 0, (64 * 128 + 1) * sizeof(float), stream); // zbuf + pen

    convert_stats<<<dim3(64, 16), 256, 0, stream>>>(x, xb, p1, p2);
    prep_all<<<3592, 256, 0, stream>>>(
        W[0], W[1], W[2], W[3], w1t, w2t, w3t, w4t,
        bb[0], gg[0], be[0], mm[0], vv[0],
        bb[1], gg[1], be[1], mm[1], vv[1],
        bb[2], gg[2], be[2], mm[2], vv[2],
        bb[3], gg[3], be[3], mm[3], vv[3], sb);

    gemm_bt<256, false><<<dim3(512, 4), 256, 0, stream>>>(xb, w1t, sb + 0,    sb + 512,  hA, nullptr, nullptr);
    gemm_bt<512, false><<<dim3(512, 4), 256, 0, stream>>>(hA, w2t, sb + 1024, sb + 1536, hB, nullptr, nullptr);
    gemm_bt<512, false><<<dim3(512, 4), 256, 0, stream>>>(hB, w3t, sb + 2048, sb + 2560, hA, nullptr, nullptr);
    gemm_bt<512, true ><<<dim3(512, 4), 256, 0, stream>>>(hA, w4t, sb + 3072, sb + 3584, hB, Wa, Apart);

    seg_softmax<<<64, 1024, 0, stream>>>(Apart, As, pen);
    pooled_k<<<dim3(64, 4, 8), 256, 0, stream>>>(As, hB, pp);
    head1<<<dim3(64, 9), 128, 0, stream>>>(pp, p1, p2, Wo1, zbuf);
    head2<<<64, 128, 0, stream>>>(zbuf, bo1, go, beo, mo, vo, Wo2, bo2,
                                  pen, (float*)d_out);
}

// Round 5
// 495.690 us; speedup vs baseline: 1.5352x; 1.0344x over previous
//
#include <hip/hip_runtime.h>
#include <cstdint>
#include <cstddef>

typedef __bf16 bf16;
typedef __bf16 bf16x4 __attribute__((ext_vector_type(4)));
typedef __bf16 bf16x8 __attribute__((ext_vector_type(8)));
typedef float  f32x4  __attribute__((ext_vector_type(4)));
typedef unsigned int uint;

#define EPS 1e-5f

// ---------------------------------------------------------------------------
// async global->LDS, 16B per lane. LDS dest is wave-uniform base + lane*16.
// ---------------------------------------------------------------------------
__device__ __forceinline__ void load_lds16(const void* g, void* l) {
    typedef __attribute__((address_space(1))) void gvoid;
    typedef __attribute__((address_space(3))) void lvoid;
    gvoid* gp = (gvoid*)(unsigned long long)(uintptr_t)g;
    lvoid* lp = (lvoid*)(unsigned int)(uintptr_t)l;
    __builtin_amdgcn_global_load_lds(gp, lp, 16, 0, 0);
}

// ---------------------------------------------------------------------------
// fused: x -> bf16 copy + per-(b,d) partial sums for mean/std. grid (64,16)
// ---------------------------------------------------------------------------
__global__ __launch_bounds__(256)
void convert_stats(const float* __restrict__ x, bf16* __restrict__ xb,
                   float* __restrict__ p1, float* __restrict__ p2)
{
    const int b = blockIdx.x, lc = blockIdx.y, d = threadIdx.x;
    const size_t base = ((size_t)b * 1024 + lc * 64) * 256;
    float s = 0.f, s2 = 0.f;
    #pragma unroll 4
    for (int l = 0; l < 64; l++) {
        float v = x[base + (size_t)l * 256 + d];
        xb[base + (size_t)l * 256 + d] = (bf16)v;
        s += v; s2 += v * v;
    }
    p1[((size_t)lc * 64 + b) * 256 + d] = s;
    p2[((size_t)lc * 64 + b) * 256 + d] = s2;
}

// ---------------------------------------------------------------------------
// all weight prep in ONE dispatch: 4 transposes + 4 scale/bias. 3592 blocks.
// ---------------------------------------------------------------------------
__global__ void prep_all(
    const float* __restrict__ W1, const float* __restrict__ W2,
    const float* __restrict__ W3, const float* __restrict__ W4,
    bf16* __restrict__ t1, bf16* __restrict__ t2,
    bf16* __restrict__ t3, bf16* __restrict__ t4,
    const float* b1, const float* g1, const float* be1, const float* m1, const float* v1,
    const float* b2, const float* g2, const float* be2, const float* m2, const float* v2,
    const float* b3, const float* g3, const float* be3, const float* m3, const float* v3,
    const float* b4, const float* g4, const float* be4, const float* m4, const float* v4,
    float* __restrict__ sb)
{
    const int bid = blockIdx.x, tid = threadIdx.x;
    if (bid < 512) {                       // W1: 512x256 (Wt[n][k])
        int idx = bid * 256 + tid;
        int n = idx >> 8, k = idx & 255;
        t1[idx] = (bf16)W1[k * 512 + n];
    } else if (bid < 3584) {               // W2/W3/W4: 512x512 each
        int r = bid - 512;
        int which = r >> 10;               // 1024 blocks each
        int idx = (r & 1023) * 256 + tid;
        int n = idx >> 9, k = idx & 511;
        const float* W = which == 0 ? W2 : (which == 1 ? W3 : W4);
        bf16* Wt       = which == 0 ? t2 : (which == 1 ? t3 : t4);
        Wt[idx] = (bf16)W[k * 512 + n];
    } else {                               // scale/bias: 8 blocks
        int r = bid - 3584;
        int lay = r >> 1;
        int j = (r & 1) * 256 + tid;
        const float *b, *g, *be, *m, *v;
        switch (lay) {
            case 0: b=b1; g=g1; be=be1; m=m1; v=v1; break;
            case 1: b=b2; g=g2; be=be2; m=m2; v=v2; break;
            case 2: b=b3; g=g3; be=be3; m=m3; v=v3; break;
            default:b=b4; g=g4; be=be4; m=m4; v=v4; break;
        }
        float sj = g[j] * rsqrtf(v[j] + EPS);
        sb[lay * 1024 + j]       = sj;
        sb[lay * 1024 + 512 + j] = (b[j] - m[j]) * sj + be[j];
    }
}

// ---------------------------------------------------------------------------
// GEMM: C[M,512] = relu( (A[M,K] @ Wt[512,K]^T) * s + t ), bf16 out
// 128x256 tile, BK=32: 32 MFMAs per barrier-drain (2x the 128x128 config).
// 4 waves as 2m x 2n; wave tile 64x128; acc 4x8 f32x4 (128 regs).
// ---------------------------------------------------------------------------
template<int K>
__global__ __launch_bounds__(256, 2)
void gemm_bt(const bf16* __restrict__ A, const bf16* __restrict__ Bt,
             const float* __restrict__ sc, const float* __restrict__ bi,
             bf16* __restrict__ C)
{
    __shared__ __align__(16) bf16 As[128 * 32];   // 8 KB
    __shared__ __align__(16) bf16 Bs[256 * 32];   // 16 KB

    const int tid  = threadIdx.x;
    const int lane = tid & 63;
    const int wid  = tid >> 6;
    const int wm   = wid >> 1;            // 0..1 (m half)
    const int wn   = wid & 1;             // 0..1 (n half)
    const size_t m0 = (size_t)blockIdx.x * 128;
    const int    n0 = blockIdx.y * 256;

    const int r0 = tid >> 2;              // staging row within 64-row group
    const int cc = tid & 3;               // 8-elem chunk within 32-col row
    bf16* AsW = &As[(tid & 192) * 8];     // wave-uniform base (+c*2048)
    bf16* BsW = &Bs[(tid & 192) * 8];

    f32x4 acc[4][8] = {};
    const int quad = lane >> 4;
    const int l16  = lane & 15;

    for (int k0 = 0; k0 < K; k0 += 32) {
        load_lds16(&A [(m0 +      r0) * K + k0 + cc * 8], AsW);
        load_lds16(&A [(m0 + 64 + r0) * K + k0 + cc * 8], AsW + 2048);
        load_lds16(&Bt[(size_t)(n0 +       r0) * K + k0 + cc * 8], BsW);
        load_lds16(&Bt[(size_t)(n0 +  64 + r0) * K + k0 + cc * 8], BsW + 2048);
        load_lds16(&Bt[(size_t)(n0 + 128 + r0) * K + k0 + cc * 8], BsW + 4096);
        load_lds16(&Bt[(size_t)(n0 + 192 + r0) * K + k0 + cc * 8], BsW + 6144);
        __syncthreads();   // drains vmcnt -> LDS visible

        bf16x8 af[4], bfr[8];
        #pragma unroll
        for (int i = 0; i < 4; i++)
            af[i] = *(const bf16x8*)&As[(wm * 64 + i * 16 + l16) * 32 + quad * 8];
        #pragma unroll
        for (int j = 0; j < 8; j++)
            bfr[j] = *(const bf16x8*)&Bs[(wn * 128 + j * 16 + l16) * 32 + quad * 8];
        #pragma unroll
        for (int i = 0; i < 4; i++)
            #pragma unroll
            for (int j = 0; j < 8; j++)
                acc[i][j] = __builtin_amdgcn_mfma_f32_16x16x32_bf16(af[i], bfr[j], acc[i][j], 0, 0, 0);
        __syncthreads();   // before next staging overwrites LDS
    }

    // epilogue: C/D layout col = lane&15, row = quad*4 + r  [m89/m91 verified]
    #pragma unroll
    for (int j = 0; j < 8; j++) {
        const int col = n0 + wn * 128 + j * 16 + l16;
        const float s = sc[col], t = bi[col];
        #pragma unroll
        for (int i = 0; i < 4; i++) {
            const size_t rowb = m0 + wm * 64 + i * 16 + quad * 4;
            #pragma unroll
            for (int r = 0; r < 4; r++) {
                float v = acc[i][j][r] * s + t;
                v = v > 0.f ? v : 0.f;
                C[(rowb + r) * 512 + col] = (bf16)v;
            }
        }
    }
}

// ---------------------------------------------------------------------------
// A[N,8] = h4[N,512](bf16) @ Wa[512,8](f32)
// ---------------------------------------------------------------------------
__global__ __launch_bounds__(256)
void compute_A(const bf16* __restrict__ h, const float* __restrict__ Wa,
               float* __restrict__ A)
{
    __shared__ float WaL[512 * 8];
    const int tid = threadIdx.x;
    for (int i = tid; i < 4096; i += 256) WaL[i] = Wa[i];
    __syncthreads();
    const size_t row = (size_t)blockIdx.x * 32 + (tid >> 3);
    const int r = tid & 7;
    const bf16* hp = h + row * 512;
    float acc0 = 0.f, acc1 = 0.f;
    #pragma unroll 4
    for (int k8 = 0; k8 < 64; k8 += 2) {
        bf16x8 h0 = *(const bf16x8*)&hp[k8 * 8];
        bf16x8 h1 = *(const bf16x8*)&hp[k8 * 8 + 8];
        #pragma unroll
        for (int j = 0; j < 8; j++) {
            acc0 += (float)h0[j] * WaL[(k8 * 8 + j) * 8 + r];
            acc1 += (float)h1[j] * WaL[(k8 * 8 + 8 + j) * 8 + r];
        }
    }
    A[row * 8 + r] = acc0 + acc1;
}

// ---------------------------------------------------------------------------
// per-segment softmax over L (8 cols) + penalty. 1024 threads.
// ---------------------------------------------------------------------------
__global__ __launch_bounds__(1024)
void seg_softmax(const float* __restrict__ A, float* __restrict__ Asg,
                 float* __restrict__ pen)
{
    __shared__ float AsL[8192];
    __shared__ float red[1024];
    __shared__ float amax[8], asum[8];
    const int b = blockIdx.x, tid = threadIdx.x;
    const float* Ab = A + (size_t)b * 8192;
    for (int i = tid * 4; i < 8192; i += 4096)
        *(float4*)&AsL[i] = *(const float4*)&Ab[i];
    __syncthreads();
    const int r = tid & 7, chunk = tid >> 3;      // 128 chunks x 8 rows
    float pm = -1e30f;
    for (int l = chunk * 8; l < chunk * 8 + 8; l++) pm = fmaxf(pm, AsL[l * 8 + r]);
    red[tid] = pm;
    __syncthreads();
    if (tid < 512) red[tid] = fmaxf(red[tid], red[tid + 512]); __syncthreads();
    if (tid < 256) red[tid] = fmaxf(red[tid], red[tid + 256]); __syncthreads();
    if (tid < 128) red[tid] = fmaxf(red[tid], red[tid + 128]); __syncthreads();
    if (tid <  64) red[tid] = fmaxf(red[tid], red[tid +  64]); __syncthreads();
    if (tid <  32) red[tid] = fmaxf(red[tid], red[tid +  32]); __syncthreads();
    if (tid <  16) red[tid] = fmaxf(red[tid], red[tid +  16]); __syncthreads();
    if (tid <   8) amax[tid] = fmaxf(red[tid], red[tid + 8]);  __syncthreads();
    const float mr = amax[r];
    float ps = 0.f;
    for (int l = chunk * 8; l < chunk * 8 + 8; l++) {
        float e = expf(AsL[l * 8 + r] - mr);
        AsL[l * 8 + r] = e;
        ps += e;
    }
    red[tid] = ps;
    __syncthreads();
    if (tid < 512) red[tid] += red[tid + 512]; __syncthreads();
    if (tid < 256) red[tid] += red[tid + 256]; __syncthreads();
    if (tid < 128) red[tid] += red[tid + 128]; __syncthreads();
    if (tid <  64) red[tid] += red[tid +  64]; __syncthreads();
    if (tid <  32) red[tid] += red[tid +  32]; __syncthreads();
    if (tid <  16) red[tid] += red[tid +  16]; __syncthreads();
    if (tid <   8) asum[tid] = red[tid] + red[tid + 8];        __syncthreads();
    const float inv = 1.f / asum[r];
    for (int l = chunk * 8; l < chunk * 8 + 8; l++) AsL[l * 8 + r] *= inv;
    __syncthreads();
    for (int i = tid * 4; i < 8192; i += 4096)
        *(float4*)&Asg[(size_t)b * 8192 + i] = *(const float4*)&AsL[i];
    __syncthreads();
    // penalty: 64 (rr,ss) pairs x 16 l-chunks of 64
    {
        const int p = tid & 63, ch = tid >> 6;
        const int rr = p >> 3, ss = p & 7;
        float dot = 0.f;
        for (int l = ch * 64; l < ch * 64 + 64; l++)
            dot += AsL[l * 8 + rr] * AsL[l * 8 + ss];
        red[tid] = dot;
    }
    __syncthreads();
    if (tid < 512) red[tid] += red[tid + 512]; __syncthreads();
    if (tid < 256) red[tid] += red[tid + 256]; __syncthreads();
    if (tid < 128) red[tid] += red[tid + 128]; __syncthreads();
    if (tid < 64) {
        float d = red[tid] + red[tid + 64] - 1.f;
        red[tid] = d * d;
    }
    __syncthreads();
    if (tid == 0) {
        float s = 0.f;
        for (int i = 0; i < 64; i++) s += red[i];
        atomicAdd(pen, s);
    }
}

// ---------------------------------------------------------------------------
// pooled partials: grid (64, 4 col-chunks, 8 l-chunks of 128)
// ---------------------------------------------------------------------------
__global__ __launch_bounds__(256)
void pooled_k(const float* __restrict__ Asg, const bf16* __restrict__ h,
              float* __restrict__ pp)
{
    const int b = blockIdx.x;
    const int cc0 = blockIdx.y * 128;
    const int lc = blockIdx.z;
    const int tid = threadIdx.x;
    const int c = tid & 127, rg = tid >> 7;
    float a0 = 0, a1 = 0, a2 = 0, a3 = 0;
    const float* Asb = Asg + (size_t)b * 8192 + (size_t)lc * 128 * 8 + rg * 4;
    const bf16* hb = h + ((size_t)b * 1024 + lc * 128) * 512 + cc0 + c;
    #pragma unroll 4
    for (int l = 0; l < 128; l++) {
        float4 a = *(const float4*)&Asb[(size_t)l * 8];
        float hv = (float)hb[(size_t)l * 512];
        a0 += a.x * hv; a1 += a.y * hv; a2 += a.z * hv; a3 += a.w * hv;
    }
    float* pb = pp + ((size_t)lc * 64 + b) * 4096 + (rg * 4) * 512 + cc0 + c;
    pb[0] = a0; pb[512] = a1; pb[1024] = a2; pb[1536] = a3;
}

// ---------------------------------------------------------------------------
// head pass 1: z[b][c] += feat-chunk @ Wo1-slice. grid (64, 9)
// kc==8 computes mean/std inline from the convert_stats partials.
// ---------------------------------------------------------------------------
__global__ __launch_bounds__(128)
void head1(const float* __restrict__ pp, const float* __restrict__ p1,
           const float* __restrict__ p2, const float* __restrict__ Wo1,
           float* __restrict__ zbuf)
{
    __shared__ float f[512];
    const int b = blockIdx.x, kc = blockIdx.y, tid = threadIdx.x;
    if (kc < 8) {
        for (int j = tid; j < 512; j += 128) {
            const size_t i = (size_t)kc * 512 + j;
            float s = 0.f;
            #pragma unroll
            for (int lc = 0; lc < 8; lc++)
                s += pp[((size_t)lc * 64 + b) * 4096 + i];
            f[j] = s;
        }
    } else {
        for (int j = tid; j < 256; j += 128) {
            float s = 0.f, s2 = 0.f;
            #pragma unroll
            for (int lc = 0; lc < 16; lc++) {
                s  += p1[((size_t)lc * 64 + b) * 256 + j];
                s2 += p2[((size_t)lc * 64 + b) * 256 + j];
            }
            float m = s * (1.f / 1024.f);
            float var = (s2 - s * m) * (1.f / 1023.f);
            f[j]       = m;
            f[256 + j] = sqrtf(fmaxf(var, 0.f));
        }
    }
    __syncthreads();
    const float* Wp = Wo1 + (size_t)kc * 512 * 128 + tid;
    float z = 0.f;
    #pragma unroll 8
    for (int j = 0; j < 512; j++) z += f[j] * Wp[(size_t)j * 128];
    atomicAdd(&zbuf[b * 128 + tid], z);
}

// ---------------------------------------------------------------------------
// head pass 2: BN+relu -> @ Wo2 -> log_softmax; b==0 writes penalty
// ---------------------------------------------------------------------------
__global__ __launch_bounds__(128)
void head2(const float* __restrict__ zbuf, const float* __restrict__ bo1,
           const float* __restrict__ go, const float* __restrict__ beo,
           const float* __restrict__ mo, const float* __restrict__ vo,
           const float* __restrict__ Wo2, const float* __restrict__ bo2,
           const float* __restrict__ pen, float* __restrict__ out)
{
    __shared__ float o[128];
    __shared__ float lg[4];
    const int b = blockIdx.x, tid = threadIdx.x;
    float z = zbuf[b * 128 + tid];
    float s = go[tid] * rsqrtf(vo[tid] + EPS);
    float t = (bo1[tid] - mo[tid]) * s + beo[tid];
    float ov = z * s + t;
    o[tid] = ov > 0.f ? ov : 0.f;
    __syncthreads();
    if (tid < 4) {
        float acc = bo2[tid];
        for (int j = 0; j < 128; j++) acc += o[j] * Wo2[j * 4 + tid];
        lg[tid] = acc;
    }
    __syncthreads();
    if (tid == 0) {
        float m = fmaxf(fmaxf(lg[0], lg[1]), fmaxf(lg[2], lg[3]));
        float sum = 0.f;
        for (int k = 0; k < 4; k++) sum += expf(lg[k] - m);
        float lse = m + logf(sum);
        for (int k = 0; k < 4; k++) out[b * 4 + k] = lg[k] - lse;
        if (b == 0) out[256] = pen[0];
    }
}

// ---------------------------------------------------------------------------
extern "C" void kernel_launch(void* const* d_in, const int* in_sizes, int n_in,
                              void* d_out, int out_size, void* d_ws, size_t ws_size,
                              hipStream_t stream)
{
    const float* x   = (const float*)d_in[0];
    const float* Wa  = (const float*)d_in[2];
    const float* Wo1 = (const float*)d_in[3];
    const float* bo1 = (const float*)d_in[4];
    const float* go  = (const float*)d_in[5];
    const float* beo = (const float*)d_in[6];
    const float* mo  = (const float*)d_in[7];
    const float* vo  = (const float*)d_in[8];
    const float* Wo2 = (const float*)d_in[9];
    const float* bo2 = (const float*)d_in[10];
    const float *W[4], *bb[4], *gg[4], *be[4], *mm[4], *vv[4];
    for (int l = 0; l < 4; l++) {
        W[l]  = (const float*)d_in[11 + 6 * l + 0];
        bb[l] = (const float*)d_in[11 + 6 * l + 1];
        gg[l] = (const float*)d_in[11 + 6 * l + 2];
        be[l] = (const float*)d_in[11 + 6 * l + 3];
        mm[l] = (const float*)d_in[11 + 6 * l + 4];
        vv[l] = (const float*)d_in[11 + 6 * l + 5];
    }

    char* w = (char*)d_ws;
    bf16* xb  = (bf16*)w;  w += (size_t)65536 * 256 * 2;   // 32 MB
    bf16* hA  = (bf16*)w;  w += (size_t)65536 * 512 * 2;   // 64 MB
    bf16* hB  = (bf16*)w;  w += (size_t)65536 * 512 * 2;   // 64 MB
    bf16* w1t = (bf16*)w;  w += (size_t)512 * 256 * 2;
    bf16* w2t = (bf16*)w;  w += (size_t)512 * 512 * 2;
    bf16* w3t = (bf16*)w;  w += (size_t)512 * 512 * 2;
    bf16* w4t = (bf16*)w;  w += (size_t)512 * 512 * 2;
    float* sb = (float*)w; w += (size_t)4 * 1024 * 4;      // [layer][s|t][512]
    float* Ab = (float*)w; w += (size_t)65536 * 8 * 4;
    float* As = (float*)w; w += (size_t)65536 * 8 * 4;
    float* pp = (float*)w; w += (size_t)8 * 64 * 4096 * 4; // pooled partials
    float* p1 = (float*)w; w += (size_t)16 * 64 * 256 * 4;
    float* p2 = (float*)w; w += (size_t)16 * 64 * 256 * 4;
    float* zbuf = (float*)w; w += (size_t)64 * 128 * 4;
    float* pen = (float*)w;

    hipMemsetAsync(zbuf, 0, (64 * 128 + 1) * sizeof(float), stream); // zbuf + pen

    convert_stats<<<dim3(64, 16), 256, 0, stream>>>(x, xb, p1, p2);
    prep_all<<<3592, 256, 0, stream>>>(
        W[0], W[1], W[2], W[3], w1t, w2t, w3t, w4t,
        bb[0], gg[0], be[0], mm[0], vv[0],
        bb[1], gg[1], be[1], mm[1], vv[1],
        bb[2], gg[2], be[2], mm[2], vv[2],
        bb[3], gg[3], be[3], mm[3], vv[3], sb);

    gemm_bt<256><<<dim3(512, 2), 256, 0, stream>>>(xb, w1t, sb + 0,    sb + 512,  hA);
    gemm_bt<512><<<dim3(512, 2), 256, 0, stream>>>(hA, w2t, sb + 1024, sb + 1536, hB);
    gemm_bt<512><<<dim3(512, 2), 256, 0, stream>>>(hB, w3t, sb + 2048, sb + 2560, hA);
    gemm_bt<512><<<dim3(512, 2), 256, 0, stream>>>(hA, w4t, sb + 3072, sb + 3584, hB);

    compute_A<<<2048, 256, 0, stream>>>(hB, Wa, Ab);
    seg_softmax<<<64, 1024, 0, stream>>>(Ab, As, pen);
    pooled_k<<<dim3(64, 4, 8), 256, 0, stream>>>(As, hB, pp);
    head1<<<dim3(64, 9), 128, 0, stream>>>(pp, p1, p2, Wo1, zbuf);
    head2<<<64, 128, 0, stream>>>(zbuf, bo1, go, beo, mo, vo, Wo2, bo2,
                                  pen, (float*)d_out);
}